// Round 12
// baseline (241.076 us; speedup 1.0000x reference)
//
#include <hip/hip_runtime.h>
#include <stdint.h>
#include <math.h>

// ---------------- types / helpers ----------------
typedef __attribute__((ext_vector_type(8))) short bf16x8;
typedef __attribute__((ext_vector_type(4))) short s16x4;
typedef __attribute__((ext_vector_type(8))) short s16x8;
typedef __attribute__((ext_vector_type(4))) float f32x4;
typedef __attribute__((ext_vector_type(2))) uint32_t u32x2;

#define DEVI __device__ __forceinline__

constexpr int Bn = 2, Tn = 1024, Cn = 768, Hn = 12, HDn = 64;
constexpr int N3 = 3 * Cn;          // 2304
constexpr int Mrows = Bn * Tn;      // 2048
constexpr size_t SZy = (size_t)Mrows * Cn;  // elems per [B,T,C] slice

template <int V> struct IntC { static constexpr int value = V; };

DEVI short f2bf(float f) {
  union { float f; uint32_t u; } v; v.f = f;
  uint32_t u = v.u;
  return (short)((u + 0x7FFFu + ((u >> 16) & 1u)) >> 16);  // RNE
}
DEVI float bf2f(short b) {
  union { uint32_t u; float f; } v; v.u = ((uint32_t)(uint16_t)b) << 16;
  return v.f;
}
DEVI float fexp2(float x) { return __builtin_exp2f(x); }
// pack two f32 -> two bf16 in one u32 (RNE), single HW instr (T12)
DEVI uint32_t cvtpk(float lo, float hi) {
  uint32_t r;
  asm("v_cvt_pk_bf16_f32 %0, %1, %2" : "=v"(r) : "v"(lo), "v"(hi));
  return r;
}
// async global->LDS, 16B per lane. LDS dest = wave-uniform base + lane*16 (linear);
// global src is per-lane (pre-swizzle the source when a swizzled layout is wanted).
DEVI void cp16(void* lds, const void* g) {
  __builtin_amdgcn_global_load_lds(
      (const __attribute__((address_space(1))) uint32_t*)(uintptr_t)g,
      (__attribute__((address_space(3))) uint32_t*)(uint32_t)(uintptr_t)lds,
      16, 0, 0);
}
DEVI f32x4 fz() { f32x4 z; z[0] = 0.f; z[1] = 0.f; z[2] = 0.f; z[3] = 0.f; return z; }
DEVI void wait_all() {
  asm volatile("s_waitcnt vmcnt(0) lgkmcnt(0)" ::: "memory");
  __builtin_amdgcn_sched_barrier(0);
}

// ---------------- prep kernels (fp32 -> bf16) ----------------
__global__ void prep_x(const float* __restrict__ x, const float* __restrict__ xl,
                       const float* __restrict__ xu, short* __restrict__ xb,
                       short* __restrict__ mb, short* __restrict__ rb) {
  int i = blockIdx.x * 256 + threadIdx.x;           // 4 elems/thread, exact grid
  float4 vx = ((const float4*)x)[i];
  float4 vl = ((const float4*)xl)[i];
  float4 vu = ((const float4*)xu)[i];
  s16x4 a, m_, g;
  a[0] = f2bf(vx.x); a[1] = f2bf(vx.y); a[2] = f2bf(vx.z); a[3] = f2bf(vx.w);
  m_[0] = f2bf(0.5f * (vl.x + vu.x)); m_[1] = f2bf(0.5f * (vl.y + vu.y));
  m_[2] = f2bf(0.5f * (vl.z + vu.z)); m_[3] = f2bf(0.5f * (vl.w + vu.w));
  g[0] = f2bf(0.5f * (vu.x - vl.x)); g[1] = f2bf(0.5f * (vu.y - vl.y));
  g[2] = f2bf(0.5f * (vu.z - vl.z)); g[3] = f2bf(0.5f * (vu.w - vl.w));
  ((s16x4*)xb)[i] = a; ((s16x4*)mb)[i] = m_; ((s16x4*)rb)[i] = g;
}
// merged W-prep: blocks [0,1728) convert W_attn -> wb,|W|->awb; [1728,2304) W_proj -> wpb
__global__ void prep_wall(const float* __restrict__ Wa, const float* __restrict__ Wp,
                          short* __restrict__ wb, short* __restrict__ awb,
                          short* __restrict__ wpb) {
  const int bid = blockIdx.x;
  if (bid < 1728) {
    int i = bid * 256 + threadIdx.x;
    float4 v = ((const float4*)Wa)[i];
    s16x4 a, b2;
    a[0] = f2bf(v.x); a[1] = f2bf(v.y); a[2] = f2bf(v.z); a[3] = f2bf(v.w);
    b2[0] = f2bf(fabsf(v.x)); b2[1] = f2bf(fabsf(v.y));
    b2[2] = f2bf(fabsf(v.z)); b2[3] = f2bf(fabsf(v.w));
    ((s16x4*)wb)[i] = a; ((s16x4*)awb)[i] = b2;
  } else {
    int i = (bid - 1728) * 256 + threadIdx.x;
    float4 v = ((const float4*)Wp)[i];
    s16x4 a;
    a[0] = f2bf(v.x); a[1] = f2bf(v.y); a[2] = f2bf(v.z); a[3] = f2bf(v.w);
    ((s16x4*)wpb)[i] = a;
  }
}

// ---------------- fused input GEMM: qkv / lower / upper in one launch ----------------
// acc0 = x @ W^T ; acc1 = mid @ W^T ; acc2 = rad @ |W|^T
// qkv = acc0 ; low = acc1 - acc2 ; up = acc1 + acc2
// BM=64, BN=128, wave-tile 32x64, grid(32, 18).
// (256,3): 170-VGPR budget. (256,4) caps at 128 and SPILLS (R9: 295 MB scratch writes).
__launch_bounds__(256, 3)
__global__ void gemm_qkv3(const short* __restrict__ A0, const short* __restrict__ A1,
                          const short* __restrict__ A2, const short* __restrict__ B0,
                          const short* __restrict__ B1, short* __restrict__ qkv,
                          short* __restrict__ low, short* __restrict__ up) {
  constexpr int BM = 64, BN = 128;
  __shared__ short At[3 * BM * 32];   // 12 KB
  __shared__ short Bt[2 * BN * 32];   // 16 KB
  const int tid = threadIdx.x, wave = tid >> 6, lane = tid & 63;
  const int g = lane >> 4, q = lane & 15;
  const int wm = wave >> 1, wn = wave & 1;
  const int brow = blockIdx.x * BM, bcol = blockIdx.y * BN;
  const short* As[3] = {A0, A1, A2};
  const short* Bs[2] = {B0, B1};

  f32x4 acc[3][2][4];
#pragma unroll
  for (int a = 0; a < 3; a++)
#pragma unroll
    for (int m = 0; m < 2; m++)
#pragma unroll
      for (int n = 0; n < 4; n++) acc[a][m][n] = fz();

  const int arow = tid >> 2, ac = tid & 3;           // A: 1 chunk/thread per tile
  for (int kt = 0; kt < Cn / 32; ++kt) {
#pragma unroll
    for (int a = 0; a < 3; a++)
      cp16((char*)At + a * 4096 + tid * 16,
           As[a] + (size_t)(brow + arow) * Cn + (kt * 32 + ac * 8));
#pragma unroll
    for (int b2 = 0; b2 < 2; b2++)
#pragma unroll
      for (int ii = 0; ii < 2; ++ii) {               // B: 128x32 tile, 2/thread
        int i = wave * 2 + ii;
        int ch = i * 64 + lane, row = ch >> 2, c = ch & 3;
        cp16((char*)Bt + b2 * 8192 + i * 1024,
             Bs[b2] + (size_t)(bcol + row) * Cn + (kt * 32 + c * 8));
      }
    __syncthreads();
    bf16x8 bfr[2][4];
#pragma unroll
    for (int b2 = 0; b2 < 2; b2++)
#pragma unroll
      for (int n = 0; n < 4; n++) {
        int r = wn * 64 + n * 16 + q;
        bfr[b2][n] = *(const bf16x8*)&Bt[b2 * (BN * 32) + r * 32 + g * 8];
      }
#pragma unroll
    for (int a = 0; a < 3; a++) {
      bf16x8 af[2];
#pragma unroll
      for (int m = 0; m < 2; m++) {
        int r = wm * 32 + m * 16 + q;
        af[m] = *(const bf16x8*)&At[a * (BM * 32) + r * 32 + g * 8];
      }
      const int bs = (a == 2) ? 1 : 0;
#pragma unroll
      for (int m = 0; m < 2; m++)
#pragma unroll
        for (int n = 0; n < 4; n++)
          acc[a][m][n] = __builtin_amdgcn_mfma_f32_16x16x32_bf16(
              af[m], bfr[bs][n], acc[a][m][n], 0, 0, 0);
    }
    __syncthreads();
  }
#pragma unroll
  for (int m = 0; m < 2; m++)
#pragma unroll
    for (int n = 0; n < 4; n++)
#pragma unroll
      for (int r = 0; r < 4; r++) {
        int row = brow + wm * 32 + m * 16 + g * 4 + r;
        int col = bcol + wn * 64 + n * 16 + q;
        size_t idx = (size_t)row * N3 + col;
        float v0 = acc[0][m][n][r], v1 = acc[1][m][n][r], v2 = acc[2][m][n][r];
        qkv[idx] = f2bf(v0);
        low[idx] = f2bf(v1 - v2);
        up[idx]  = f2bf(v1 + v2);
      }
}

// ---------------- projection GEMM: 3 outputs in one launch (grid.z selects A) -------
// BM=64, BN=128, grid(32, 6, 3)  (known-good (256,4): low VGPR kernel, no spill)
__launch_bounds__(256, 4)
__global__ void gemm_proj(const short* __restrict__ A0, const short* __restrict__ A1,
                          const short* __restrict__ A2, const short* __restrict__ Bw,
                          float* __restrict__ out) {
  constexpr int BM = 64, BN = 128;
  __shared__ short At[BM * 32];
  __shared__ short Bt[BN * 32];
  const short* Ap = blockIdx.z == 0 ? A0 : (blockIdx.z == 1 ? A1 : A2);
  float* op = out + (size_t)blockIdx.z * SZy;
  const int tid = threadIdx.x, wave = tid >> 6, lane = tid & 63;
  const int wm = wave >> 1, wn = wave & 1;
  const int brow = blockIdx.x * BM, bcol = blockIdx.y * BN;

  f32x4 acc[2][4];
#pragma unroll
  for (int m = 0; m < 2; m++)
#pragma unroll
    for (int n = 0; n < 4; n++) acc[m][n] = fz();

  const int chunk = wave * 64 + lane, srow = chunk >> 2, sc = chunk & 3;
  for (int kt = 0; kt < Cn / 32; ++kt) {
    cp16((char*)At + wave * 1024, Ap + (size_t)(brow + srow) * Cn + (kt * 32 + sc * 8));
#pragma unroll
    for (int ii = 0; ii < 2; ++ii) {
      int i = wave * 2 + ii;
      int ch = i * 64 + lane, row = ch >> 2, c = ch & 3;
      cp16((char*)Bt + i * 1024, Bw + (size_t)(bcol + row) * Cn + (kt * 32 + c * 8));
    }
    __syncthreads();
    bf16x8 af[2], bfr[4];
#pragma unroll
    for (int m = 0; m < 2; m++) {
      int r = wm * 32 + m * 16 + (lane & 15);
      af[m] = *(const bf16x8*)&At[r * 32 + (lane >> 4) * 8];
    }
#pragma unroll
    for (int n = 0; n < 4; n++) {
      int r = wn * 64 + n * 16 + (lane & 15);
      bfr[n] = *(const bf16x8*)&Bt[r * 32 + (lane >> 4) * 8];
    }
#pragma unroll
    for (int m = 0; m < 2; m++)
#pragma unroll
      for (int n = 0; n < 4; n++)
        acc[m][n] = __builtin_amdgcn_mfma_f32_16x16x32_bf16(af[m], bfr[n], acc[m][n], 0, 0, 0);
    __syncthreads();
  }
#pragma unroll
  for (int m = 0; m < 2; m++)
#pragma unroll
    for (int n = 0; n < 4; n++)
#pragma unroll
      for (int r = 0; r < 4; r++) {
        int row = brow + wm * 32 + m * 16 + (lane >> 4) * 4 + r;
        int col = bcol + wn * 64 + n * 16 + (lane & 15);
        op[(size_t)row * Cn + col] = acc[m][n][r];
      }
}

// ---------------- per-head V transpose (3 sources via grid.z) ----------------
__global__ void vtrans(const short* __restrict__ s0, const short* __restrict__ s1,
                       const short* __restrict__ s2, short* __restrict__ d0,
                       short* __restrict__ d1, short* __restrict__ d2) {
  __shared__ short tile[64][72];   // pad 8: rows stay 16B-aligned (144B)
  const short* src = blockIdx.z == 0 ? s0 : (blockIdx.z == 1 ? s1 : s2);
  short* dst = blockIdx.z == 0 ? d0 : (blockIdx.z == 1 ? d1 : d2);
  const int tt = blockIdx.x, bh = blockIdx.y;
  const int b = bh / Hn, h = bh % Hn;
  const int tid = threadIdx.x;
#pragma unroll
  for (int i = 0; i < 2; i++) {
    int chunk = i * 256 + tid;            // 512 chunks of 8 elems
    int t = chunk >> 3, c = chunk & 7;
    s16x8 v = *(const s16x8*)(src + (size_t)(b * Tn + tt * 64 + t) * N3 +
                              2 * Cn + h * HDn + c * 8);
    *(s16x8*)&tile[t][c * 8] = v;
  }
  __syncthreads();
#pragma unroll
  for (int i = 0; i < 2; i++) {
    int chunk = i * 256 + tid;
    int d = chunk >> 3, tc = chunk & 7;
    s16x8 v;
#pragma unroll
    for (int j = 0; j < 8; j++) v[j] = tile[tc * 8 + j][d];
    *(s16x8*)(dst + (size_t)bh * (64 * 1024) + (size_t)d * 1024 + tt * 64 + tc * 8) = v;
  }
}

// ---------------- unified flash attention (causal, swapped-QK^T, QBLK=128) --------
// grid (24 bh, 5 combo, 8 j-reversed). Each wave owns TWO 16-row q-groups (u=0,1).
// R12: V0/V1 come straight from global (vtq d-major -> per-lane 16B frag loads,
// L2-resident) instead of LDS staging; K double-buffered in LDS -> ONE barrier/iter
// whose vmcnt(0) drains a cp16 issued a full iteration earlier. vf1 is issued AFTER
// softmax so it never overlaps live sa registers (VGPR-pressure control).
// (256,3): known-safe budget. Spill tripwire: VGPR<100 + WRITE_SIZE >> 28MB.
__launch_bounds__(256, 3)
__global__ void flash_all(const short* __restrict__ qkv, const short* __restrict__ lowb,
                          const short* __restrict__ upb, const short* __restrict__ vtq,
                          const short* __restrict__ vtl, const short* __restrict__ vtu,
                          short* __restrict__ yab, short* __restrict__ comb) {
  constexpr float SCL = 0.18033688f;       // (1/sqrt(64)) * log2(e)
  constexpr float THR = 8.0f / SCL;        // defer-max threshold, raw-score domain
  __shared__ short Kt[2][64 * 64];         // 16 KB, double-buffered (src pre-swizzled)
  __shared__ short Pt[8 * 16 * 64];        // 16 KB: per (wave,u) 16q x 64k P^T
  const int tid = threadIdx.x, wave = tid >> 6, lane = tid & 63;
  const int g = lane >> 4, q = lane & 15;
  const int bh = blockIdx.x, combo = blockIdx.y;
  const int j = 7 - blockIdx.z;            // long blocks dispatch first
  const int qt0 = j * 128;
  const int b = bh / Hn, h = bh % Hn;
  const bool isMain = (combo == 4);
  const short* Qsrc = isMain ? qkv : ((combo & 2) ? upb : lowb);
  const short* Ksrc = isMain ? qkv : ((combo & 1) ? upb : lowb);
  const short* V0t = isMain ? vtq : vtl;
  const short* V1t = vtu;
  const int qswz = (q & 7) << 4;
  const int jjmax = 2 * j + 1;

  // K staging source offsets (lane-dependent, kv-invariant)
  int koff[2];
#pragma unroll
  for (int ii = 0; ii < 2; ++ii) {
    int chunk = (wave * 2 + ii) * 64 + lane, row = chunk >> 3, c = chunk & 7;
    int cg = c ^ (row & 7);
    koff[ii] = row * N3 + cg * 8;
  }
  const short* Kbase = Ksrc + (size_t)(b * Tn) * N3 + Cn + h * HDn;
  const short* V0base = V0t + (size_t)bh * (64 * 1024);
  const short* V1base = V1t + (size_t)bh * (64 * 1024);
  // per-lane V-row offsets (kv-invariant): V^T[drow=mf*16+q][... + g*8]
  int voffr[4];
#pragma unroll
  for (int mf = 0; mf < 4; mf++) voffr[mf] = (mf * 16 + q) * 1024 + g * 8;

  // Q frags (PV-style B-frag): lane holds Q[q][8 contiguous d]
  bf16x8 aq[2][2];
#pragma unroll
  for (int u = 0; u < 2; u++) {
    int trow = qt0 + u * 64 + wave * 16 + q;
    const short* qp = Qsrc + (size_t)(b * Tn + trow) * N3 + h * HDn;
#pragma unroll
    for (int s = 0; s < 2; s++) aq[u][s] = *(const bf16x8*)(qp + s * 32 + g * 8);
  }

  f32x4 o0[2][4], o1[2][4];     // o[u][mf][r]: d = mf*16 + g*4 + r, col q
  float mrow[2], lrow[2];
#pragma unroll
  for (int u = 0; u < 2; u++) {
    mrow[u] = -INFINITY; lrow[u] = 0.f;
#pragma unroll
    for (int n = 0; n < 4; n++) { o0[u][n] = fz(); o1[u][n] = fz(); }
  }

  // softmax for one q-group; sv = S^T fragment (k = m*16+g*4+r, col q)
  auto softmax_u = [&](f32x4 (&sv)[4], int u, auto diagc) {
    constexpr bool DIAG = decltype(diagc)::value;
    if constexpr (DIAG) {
      const int rhs = wave * 16 + q, kb = g * 4;
#pragma unroll
      for (int m = 0; m < 4; m++)
#pragma unroll
        for (int r = 0; r < 4; r++)
          sv[m][r] = (m * 16 + kb + r <= rhs) ? sv[m][r] : -INFINITY;
    }
    float mx = -INFINITY;
#pragma unroll
    for (int m = 0; m < 4; m++)
#pragma unroll
      for (int r = 0; r < 4; r++) mx = fmaxf(mx, sv[m][r]);
    mx = fmaxf(mx, __shfl_xor(mx, 16));
    mx = fmaxf(mx, __shfl_xor(mx, 32));
    if (!__all(mx <= mrow[u] + THR)) {     // defer-max (T13)
      float mnew = fmaxf(mrow[u], mx);
      float corr = fexp2((mrow[u] - mnew) * SCL);
      mrow[u] = mnew; lrow[u] *= corr;
#pragma unroll
      for (int n = 0; n < 4; n++) {
        o0[u][n][0] *= corr; o0[u][n][1] *= corr;
        o0[u][n][2] *= corr; o0[u][n][3] *= corr;
      }
      if (!isMain) {
#pragma unroll
        for (int n = 0; n < 4; n++) {
          o1[u][n][0] *= corr; o1[u][n][1] *= corr;
          o1[u][n][2] *= corr; o1[u][n][3] *= corr;
        }
      }
    }
    const float nms = -mrow[u] * SCL;
    float ps = 0.f;
#pragma unroll
    for (int m = 0; m < 4; m++)
#pragma unroll
      for (int r = 0; r < 4; r++) {
        float p = fexp2(fmaf(sv[m][r], SCL, nms));
        sv[m][r] = p;
        ps += p;
      }
    ps += __shfl_xor(ps, 16);
    ps += __shfl_xor(ps, 32);
    lrow[u] += ps;
    // P^T -> Pt (b64 stores; wave-private, same-wave in-order write->read)
    char* PtW = (char*)Pt + (wave * 2 + u) * 2048;
#pragma unroll
    for (int m = 0; m < 4; m++) {
      u32x2 w;
      w[0] = cvtpk(sv[m][0], sv[m][1]);
      w[1] = cvtpk(sv[m][2], sv[m][3]);
      *(u32x2*)(PtW + ((q * 128 + m * 32 + g * 8) ^ qswz)) = w;
    }
  };

  // prologue: stage K(0) into Kt[0]
#pragma unroll
  for (int ii = 0; ii < 2; ++ii)
    cp16((char*)Kt[0] + (wave * 2 + ii) * 1024, Kbase + koff[ii]);
  wait_all();
  __builtin_amdgcn_s_barrier();

  // one kv tile; M0/M1 per-group mode: 2=full, 1=diag, 0=skip
  auto kv_iter = [&](int kv, int p, auto m0c, auto m1c) {
    constexpr int M0 = decltype(m0c)::value;
    constexpr int M1 = decltype(m1c)::value;
    // V0 frags: direct global->reg (issued first, consumed after softmax)
    bf16x8 vf0[2][4];
#pragma unroll
    for (int kk = 0; kk < 2; kk++)
#pragma unroll
      for (int mf = 0; mf < 4; mf++)
        vf0[kk][mf] = *(const bf16x8*)(V0base + voffr[mf] + kv * 64 + kk * 32);
    // K(kv+1) prefetch into the alternate buffer (drained at end-of-iter barrier)
    {
      int kvn = kv + 1 > jjmax ? jjmax : kv + 1;
#pragma unroll
      for (int ii = 0; ii < 2; ++ii)
        cp16((char*)Kt[p ^ 1] + (wave * 2 + ii) * 1024,
             Kbase + (size_t)kvn * (64 * N3) + koff[ii]);
    }

    // S^T = K Q^T for both q-groups: one bk read feeds 2 MFMAs
    f32x4 sa0[4], sa1[4];
#pragma unroll
    for (int m = 0; m < 4; m++) { sa0[m] = fz(); sa1[m] = fz(); }
    __builtin_amdgcn_s_setprio(1);
#pragma unroll
    for (int m = 0; m < 4; m++) {
#pragma unroll
      for (int s = 0; s < 2; s++) {
        int krow = m * 16 + q;
        bf16x8 bk = *(const bf16x8*)((char*)Kt[p] +
            krow * 128 + ((g * 16 + s * 64) ^ ((krow & 7) << 4)));
        if constexpr (M0 > 0)
          sa0[m] = __builtin_amdgcn_mfma_f32_16x16x32_bf16(bk, aq[0][s], sa0[m], 0, 0, 0);
        if constexpr (M1 > 0)
          sa1[m] = __builtin_amdgcn_mfma_f32_16x16x32_bf16(bk, aq[1][s], sa1[m], 0, 0, 0);
      }
    }
    __builtin_amdgcn_s_setprio(0);

    if constexpr (M0 > 0) softmax_u(sa0, 0, IntC<(M0 == 1)>{});
    if constexpr (M1 > 0) softmax_u(sa1, 1, IntC<(M1 == 1)>{});

    // V1 frags issued AFTER softmax (sa regs dead -> keeps peak VGPR in budget)
    bf16x8 vf1[2][4];
    if (!isMain) {
#pragma unroll
      for (int kk = 0; kk < 2; kk++)
#pragma unroll
        for (int mf = 0; mf < 4; mf++)
          vf1[kk][mf] = *(const bf16x8*)(V1base + voffr[mf] + kv * 64 + kk * 32);
    }

    // O^T += V^T P^T: one V frag feeds 2 MFMAs (u=0,1)
    __builtin_amdgcn_s_setprio(1);
#pragma unroll
    for (int kk = 0; kk < 2; kk++) {
      bf16x8 pb0, pb1;
      if constexpr (M0 > 0)
        pb0 = *(const bf16x8*)((char*)Pt + (wave * 2 + 0) * 2048 +
                               ((q * 128 + kk * 64 + g * 16) ^ qswz));
      if constexpr (M1 > 0)
        pb1 = *(const bf16x8*)((char*)Pt + (wave * 2 + 1) * 2048 +
                               ((q * 128 + kk * 64 + g * 16) ^ qswz));
#pragma unroll
      for (int mf = 0; mf < 4; mf++) {
        if constexpr (M0 > 0)
          o0[0][mf] = __builtin_amdgcn_mfma_f32_16x16x32_bf16(vf0[kk][mf], pb0, o0[0][mf], 0, 0, 0);
        if constexpr (M1 > 0)
          o0[1][mf] = __builtin_amdgcn_mfma_f32_16x16x32_bf16(vf0[kk][mf], pb1, o0[1][mf], 0, 0, 0);
        if (!isMain) {
          if constexpr (M0 > 0)
            o1[0][mf] = __builtin_amdgcn_mfma_f32_16x16x32_bf16(vf1[kk][mf], pb0, o1[0][mf], 0, 0, 0);
          if constexpr (M1 > 0)
            o1[1][mf] = __builtin_amdgcn_mfma_f32_16x16x32_bf16(vf1[kk][mf], pb1, o1[1][mf], 0, 0, 0);
        }
      }
    }
    __builtin_amdgcn_s_setprio(0);
    // single barrier per iter: drains own K-prefetch (issued a full iter ago)
    wait_all();
    __builtin_amdgcn_s_barrier();
  };

  const int jj = 2 * j;                    // diag tile of group 0
  int p = 0;
  for (int kv = 0; kv < jj; ++kv) { kv_iter(kv, p, IntC<2>{}, IntC<2>{}); p ^= 1; }
  kv_iter(jj, p, IntC<1>{}, IntC<2>{}); p ^= 1;
  kv_iter(jj + 1, p, IntC<0>{}, IntC<1>{});

  // epilogue: lane owns row q of group u; packed 8B stores
#pragma unroll
  for (int u = 0; u < 2; u++) {
    const float inv = 1.0f / lrow[u];
    const int trow = qt0 + u * 64 + wave * 16 + q;
    const size_t rowbase = (size_t)(b * Tn + trow) * Cn + h * HDn + g * 4;
#pragma unroll
    for (int mf = 0; mf < 4; mf++) {
      size_t idx = rowbase + mf * 16;
      u32x2 v0;
      v0[0] = cvtpk(o0[u][mf][0] * inv, o0[u][mf][1] * inv);
      v0[1] = cvtpk(o0[u][mf][2] * inv, o0[u][mf][3] * inv);
      if (isMain) {
        *(u32x2*)(yab + idx) = v0;
      } else {
        u32x2 v1;
        v1[0] = cvtpk(o1[u][mf][0] * inv, o1[u][mf][1] * inv);
        v1[1] = cvtpk(o1[u][mf][2] * inv, o1[u][mf][3] * inv);
        // P >= 0 and vL <= vU  =>  P vL <= P vU elementwise
        *(u32x2*)(comb + (size_t)(2 * combo) * SZy + idx) = v0;
        *(u32x2*)(comb + (size_t)(2 * combo + 1) * SZy + idx) = v1;
      }
    }
  }
}

// ---------------- min/max reduce over the 4 bound combos ----------------
__global__ void reduce_minmax(const short* __restrict__ comb, short* __restrict__ ymn,
                              short* __restrict__ ymx) {
  int i = blockIdx.x * 256 + threadIdx.x;   // 8 elems/thread; grid = SZy/8/256 = 768
  s16x8 mn8 = ((const s16x8*)(comb + 0 * SZy))[i];
  s16x8 mx8 = ((const s16x8*)(comb + 1 * SZy))[i];
#pragma unroll
  for (int c = 1; c < 4; c++) {
    s16x8 a = ((const s16x8*)(comb + (size_t)(2 * c) * SZy))[i];
    s16x8 b2 = ((const s16x8*)(comb + (size_t)(2 * c + 1) * SZy))[i];
#pragma unroll
    for (int j = 0; j < 8; j++) {
      mn8[j] = f2bf(fminf(bf2f(mn8[j]), bf2f(a[j])));
      mx8[j] = f2bf(fmaxf(bf2f(mx8[j]), bf2f(b2[j])));
    }
  }
  ((s16x8*)ymn)[i] = mn8;
  ((s16x8*)ymx)[i] = mx8;
}

// ---------------- launch ----------------
extern "C" void kernel_launch(void* const* d_in, const int* in_sizes, int n_in,
                              void* d_out, int out_size, void* d_ws, size_t ws_size,
                              hipStream_t stream) {
  const float* x  = (const float*)d_in[0];
  const float* xl = (const float*)d_in[1];
  const float* xu = (const float*)d_in[2];
  const float* Wa = (const float*)d_in[3];
  const float* Wp = (const float*)d_in[4];
  float* out = (float*)d_out;

  char* p = (char*)d_ws;
  auto carve = [&](size_t bytes) -> char* {
    char* r = p; p += (bytes + 255) & ~(size_t)255; return r;
  };
  short* xb   = (short*)carve((size_t)Mrows * Cn * 2);
  short* midb = (short*)carve((size_t)Mrows * Cn * 2);
  short* radb = (short*)carve((size_t)Mrows * Cn * 2);
  short* wb   = (short*)carve((size_t)N3 * Cn * 2);
  short* awb  = (short*)carve((size_t)N3 * Cn * 2);
  short* wpb  = (short*)carve((size_t)Cn * Cn * 2);
  short* qkvb = (short*)carve((size_t)Mrows * N3 * 2);
  short* lowb = (short*)carve((size_t)Mrows * N3 * 2);
  short* upb  = (short*)carve((size_t)Mrows * N3 * 2);
  short* vtq  = (short*)carve((size_t)24 * 64 * 1024 * 2);
  short* vtl  = (short*)carve((size_t)24 * 64 * 1024 * 2);
  short* vtu  = (short*)carve((size_t)24 * 64 * 1024 * 2);
  short* yab  = (short*)carve(SZy * 2);
  short* ymnb = (short*)carve(SZy * 2);
  short* ymxb = (short*)carve(SZy * 2);
  short* comb = (short*)carve(8 * SZy * 2);

  // bf16 conversions (+ mid/rad, |W|) — W_attn and W_proj merged in one launch
  prep_x<<<1536, 256, 0, stream>>>(x, xl, xu, xb, midb, radb);
  prep_wall<<<2304, 256, 0, stream>>>(Wa, Wp, wb, awb, wpb);

  // qkv / lower / upper in one fused launch
  gemm_qkv3<<<dim3(32, 18), 256, 0, stream>>>(xb, midb, radb, wb, awb,
                                              qkvb, lowb, upb);

  // per-head V transposes (3 sources, one launch)
  vtrans<<<dim3(16, 24, 3), 256, 0, stream>>>(qkvb, lowb, upb, vtq, vtl, vtu);

  // all 5 attention passes in one launch (QBLK=128, V-in-reg, 1 barrier/iter)
  flash_all<<<dim3(24, 5, 8), 256, 0, stream>>>(qkvb, lowb, upb, vtq, vtl, vtu,
                                                yab, comb);

  // fold the 4 bound combos into ymin/ymax
  reduce_minmax<<<768, 256, 0, stream>>>(comb, ymnb, ymxb);

  // output projections -> d_out (y, y_lower, y_upper) in one launch
  gemm_proj<<<dim3(32, 6, 3), 256, 0, stream>>>(yab, ymnb, ymxb, wpb, out);
}

// Round 13
// 135.969 us; speedup vs baseline: 1.7730x; 1.7730x over previous
//
#include <hip/hip_runtime.h>
#include <stdint.h>
#include <math.h>

// ---------------- types / helpers ----------------
typedef __attribute__((ext_vector_type(8))) short bf16x8;
typedef __attribute__((ext_vector_type(4))) short s16x4;
typedef __attribute__((ext_vector_type(8))) short s16x8;
typedef __attribute__((ext_vector_type(4))) float f32x4;
typedef __attribute__((ext_vector_type(2))) uint32_t u32x2;

#define DEVI __device__ __forceinline__

constexpr int Bn = 2, Tn = 1024, Cn = 768, Hn = 12, HDn = 64;
constexpr int N3 = 3 * Cn;          // 2304
constexpr int Mrows = Bn * Tn;      // 2048
constexpr size_t SZy = (size_t)Mrows * Cn;  // elems per [B,T,C] slice

template <int V> struct IntC { static constexpr int value = V; };

DEVI short f2bf(float f) {
  union { float f; uint32_t u; } v; v.f = f;
  uint32_t u = v.u;
  return (short)((u + 0x7FFFu + ((u >> 16) & 1u)) >> 16);  // RNE
}
DEVI float bf2f(short b) {
  union { uint32_t u; float f; } v; v.u = ((uint32_t)(uint16_t)b) << 16;
  return v.f;
}
DEVI float fexp2(float x) { return __builtin_exp2f(x); }
// pack two f32 -> two bf16 in one u32 (RNE), single HW instr (T12)
DEVI uint32_t cvtpk(float lo, float hi) {
  uint32_t r;
  asm("v_cvt_pk_bf16_f32 %0, %1, %2" : "=v"(r) : "v"(lo), "v"(hi));
  return r;
}
// async global->LDS, 16B per lane. LDS dest = wave-uniform base + lane*16 (linear);
// global src is per-lane (pre-swizzle the source when a swizzled layout is wanted).
DEVI void cp16(void* lds, const void* g) {
  __builtin_amdgcn_global_load_lds(
      (const __attribute__((address_space(1))) uint32_t*)(uintptr_t)g,
      (__attribute__((address_space(3))) uint32_t*)(uint32_t)(uintptr_t)lds,
      16, 0, 0);
}
DEVI f32x4 fz() { f32x4 z; z[0] = 0.f; z[1] = 0.f; z[2] = 0.f; z[3] = 0.f; return z; }

// ---------------- prep kernels (fp32 -> bf16) ----------------
__global__ void prep_x(const float* __restrict__ x, const float* __restrict__ xl,
                       const float* __restrict__ xu, short* __restrict__ xb,
                       short* __restrict__ mb, short* __restrict__ rb) {
  int i = blockIdx.x * 256 + threadIdx.x;           // 4 elems/thread, exact grid
  float4 vx = ((const float4*)x)[i];
  float4 vl = ((const float4*)xl)[i];
  float4 vu = ((const float4*)xu)[i];
  s16x4 a, m_, g;
  a[0] = f2bf(vx.x); a[1] = f2bf(vx.y); a[2] = f2bf(vx.z); a[3] = f2bf(vx.w);
  m_[0] = f2bf(0.5f * (vl.x + vu.x)); m_[1] = f2bf(0.5f * (vl.y + vu.y));
  m_[2] = f2bf(0.5f * (vl.z + vu.z)); m_[3] = f2bf(0.5f * (vl.w + vu.w));
  g[0] = f2bf(0.5f * (vu.x - vl.x)); g[1] = f2bf(0.5f * (vu.y - vl.y));
  g[2] = f2bf(0.5f * (vu.z - vl.z)); g[3] = f2bf(0.5f * (vu.w - vl.w));
  ((s16x4*)xb)[i] = a; ((s16x4*)mb)[i] = m_; ((s16x4*)rb)[i] = g;
}
// merged W-prep: blocks [0,1728) convert W_attn -> wb,|W|->awb; [1728,2304) W_proj -> wpb
__global__ void prep_wall(const float* __restrict__ Wa, const float* __restrict__ Wp,
                          short* __restrict__ wb, short* __restrict__ awb,
                          short* __restrict__ wpb) {
  const int bid = blockIdx.x;
  if (bid < 1728) {
    int i = bid * 256 + threadIdx.x;
    float4 v = ((const float4*)Wa)[i];
    s16x4 a, b2;
    a[0] = f2bf(v.x); a[1] = f2bf(v.y); a[2] = f2bf(v.z); a[3] = f2bf(v.w);
    b2[0] = f2bf(fabsf(v.x)); b2[1] = f2bf(fabsf(v.y));
    b2[2] = f2bf(fabsf(v.z)); b2[3] = f2bf(fabsf(v.w));
    ((s16x4*)wb)[i] = a; ((s16x4*)awb)[i] = b2;
  } else {
    int i = (bid - 1728) * 256 + threadIdx.x;
    float4 v = ((const float4*)Wp)[i];
    s16x4 a;
    a[0] = f2bf(v.x); a[1] = f2bf(v.y); a[2] = f2bf(v.z); a[3] = f2bf(v.w);
    ((s16x4*)wpb)[i] = a;
  }
}

// ---------------- input GEMM, grid.z-split for dispatch width -------------------
// z=0: qkv = x @ W^T              (1 A-source, B=W,   8 MFMA/kstep)
// z=1: low/up = mid@W^T -/+ rad@|W|^T  (2 A-sources, B=W,|W|, 16 MFMA/kstep)
// BM=64, BN=128, wave-tile 32x64, grid(32, 18, 2) = 1152 blocks (was 576 fused:
// 2.25 blocks/CU grid-starved). LDS 24KB, VGPR ~110 < (256,3)'s 170 budget.
__launch_bounds__(256, 3)
__global__ void gemm_qkv3(const short* __restrict__ A0, const short* __restrict__ A1,
                          const short* __restrict__ A2, const short* __restrict__ B0,
                          const short* __restrict__ B1, short* __restrict__ qkv,
                          short* __restrict__ low, short* __restrict__ up) {
  constexpr int BM = 64, BN = 128;
  __shared__ short At[2 * BM * 32];   // 8 KB (z=0 uses first half)
  __shared__ short Bt[2 * BN * 32];   // 16 KB (z=0 uses first half)
  const int tid = threadIdx.x, wave = tid >> 6, lane = tid & 63;
  const int g = lane >> 4, q = lane & 15;
  const int wm = wave >> 1, wn = wave & 1;
  const int brow = blockIdx.x * BM, bcol = blockIdx.y * BN;
  const int z = blockIdx.z;

  const int arow = tid >> 2, ac = tid & 3;           // A: 1 chunk/thread per tile
  if (z == 0) {
    // ---- qkv = x @ W^T ----
    f32x4 acc[2][4];
#pragma unroll
    for (int m = 0; m < 2; m++)
#pragma unroll
      for (int n = 0; n < 4; n++) acc[m][n] = fz();
    for (int kt = 0; kt < Cn / 32; ++kt) {
      cp16((char*)At + tid * 16, A0 + (size_t)(brow + arow) * Cn + (kt * 32 + ac * 8));
#pragma unroll
      for (int ii = 0; ii < 2; ++ii) {
        int i = wave * 2 + ii;
        int ch = i * 64 + lane, row = ch >> 2, c = ch & 3;
        cp16((char*)Bt + i * 1024, B0 + (size_t)(bcol + row) * Cn + (kt * 32 + c * 8));
      }
      __syncthreads();
      bf16x8 af[2], bfr[4];
#pragma unroll
      for (int m = 0; m < 2; m++) {
        int r = wm * 32 + m * 16 + q;
        af[m] = *(const bf16x8*)&At[r * 32 + g * 8];
      }
#pragma unroll
      for (int n = 0; n < 4; n++) {
        int r = wn * 64 + n * 16 + q;
        bfr[n] = *(const bf16x8*)&Bt[r * 32 + g * 8];
      }
#pragma unroll
      for (int m = 0; m < 2; m++)
#pragma unroll
        for (int n = 0; n < 4; n++)
          acc[m][n] = __builtin_amdgcn_mfma_f32_16x16x32_bf16(af[m], bfr[n], acc[m][n], 0, 0, 0);
      __syncthreads();
    }
#pragma unroll
    for (int m = 0; m < 2; m++)
#pragma unroll
      for (int n = 0; n < 4; n++)
#pragma unroll
        for (int r = 0; r < 4; r++) {
          int row = brow + wm * 32 + m * 16 + g * 4 + r;
          int col = bcol + wn * 64 + n * 16 + q;
          qkv[(size_t)row * N3 + col] = f2bf(acc[m][n][r]);
        }
  } else {
    // ---- low/up = mid@W^T -/+ rad@|W|^T ----
    f32x4 acc[2][2][4];
#pragma unroll
    for (int a = 0; a < 2; a++)
#pragma unroll
      for (int m = 0; m < 2; m++)
#pragma unroll
        for (int n = 0; n < 4; n++) acc[a][m][n] = fz();
    const short* As[2] = {A1, A2};
    const short* Bs[2] = {B0, B1};
    for (int kt = 0; kt < Cn / 32; ++kt) {
#pragma unroll
      for (int a = 0; a < 2; a++)
        cp16((char*)At + a * 4096 + tid * 16,
             As[a] + (size_t)(brow + arow) * Cn + (kt * 32 + ac * 8));
#pragma unroll
      for (int b2 = 0; b2 < 2; b2++)
#pragma unroll
        for (int ii = 0; ii < 2; ++ii) {
          int i = wave * 2 + ii;
          int ch = i * 64 + lane, row = ch >> 2, c = ch & 3;
          cp16((char*)Bt + b2 * 8192 + i * 1024,
               Bs[b2] + (size_t)(bcol + row) * Cn + (kt * 32 + c * 8));
        }
      __syncthreads();
      bf16x8 bfr[2][4];
#pragma unroll
      for (int b2 = 0; b2 < 2; b2++)
#pragma unroll
        for (int n = 0; n < 4; n++) {
          int r = wn * 64 + n * 16 + q;
          bfr[b2][n] = *(const bf16x8*)&Bt[b2 * (BN * 32) + r * 32 + g * 8];
        }
#pragma unroll
      for (int a = 0; a < 2; a++) {
        bf16x8 af[2];
#pragma unroll
        for (int m = 0; m < 2; m++) {
          int r = wm * 32 + m * 16 + q;
          af[m] = *(const bf16x8*)&At[a * (BM * 32) + r * 32 + g * 8];
        }
#pragma unroll
        for (int m = 0; m < 2; m++)
#pragma unroll
          for (int n = 0; n < 4; n++)
            acc[a][m][n] = __builtin_amdgcn_mfma_f32_16x16x32_bf16(
                af[m], bfr[a][n], acc[a][m][n], 0, 0, 0);
      }
      __syncthreads();
    }
#pragma unroll
    for (int m = 0; m < 2; m++)
#pragma unroll
      for (int n = 0; n < 4; n++)
#pragma unroll
        for (int r = 0; r < 4; r++) {
          int row = brow + wm * 32 + m * 16 + g * 4 + r;
          int col = bcol + wn * 64 + n * 16 + q;
          size_t idx = (size_t)row * N3 + col;
          float v1 = acc[0][m][n][r], v2 = acc[1][m][n][r];
          low[idx] = f2bf(v1 - v2);
          up[idx]  = f2bf(v1 + v2);
        }
  }
}

// ---------------- projection GEMM: 3 outputs in one launch (grid.z selects A) -------
// BM=64, BN=128, grid(32, 6, 3)  (known-good (256,4): low VGPR kernel, no spill)
__launch_bounds__(256, 4)
__global__ void gemm_proj(const short* __restrict__ A0, const short* __restrict__ A1,
                          const short* __restrict__ A2, const short* __restrict__ Bw,
                          float* __restrict__ out) {
  constexpr int BM = 64, BN = 128;
  __shared__ short At[BM * 32];
  __shared__ short Bt[BN * 32];
  const short* Ap = blockIdx.z == 0 ? A0 : (blockIdx.z == 1 ? A1 : A2);
  float* op = out + (size_t)blockIdx.z * SZy;
  const int tid = threadIdx.x, wave = tid >> 6, lane = tid & 63;
  const int wm = wave >> 1, wn = wave & 1;
  const int brow = blockIdx.x * BM, bcol = blockIdx.y * BN;

  f32x4 acc[2][4];
#pragma unroll
  for (int m = 0; m < 2; m++)
#pragma unroll
    for (int n = 0; n < 4; n++) acc[m][n] = fz();

  const int chunk = wave * 64 + lane, srow = chunk >> 2, sc = chunk & 3;
  for (int kt = 0; kt < Cn / 32; ++kt) {
    cp16((char*)At + wave * 1024, Ap + (size_t)(brow + srow) * Cn + (kt * 32 + sc * 8));
#pragma unroll
    for (int ii = 0; ii < 2; ++ii) {
      int i = wave * 2 + ii;
      int ch = i * 64 + lane, row = ch >> 2, c = ch & 3;
      cp16((char*)Bt + i * 1024, Bw + (size_t)(bcol + row) * Cn + (kt * 32 + c * 8));
    }
    __syncthreads();
    bf16x8 af[2], bfr[4];
#pragma unroll
    for (int m = 0; m < 2; m++) {
      int r = wm * 32 + m * 16 + (lane & 15);
      af[m] = *(const bf16x8*)&At[r * 32 + (lane >> 4) * 8];
    }
#pragma unroll
    for (int n = 0; n < 4; n++) {
      int r = wn * 64 + n * 16 + (lane & 15);
      bfr[n] = *(const bf16x8*)&Bt[r * 32 + (lane >> 4) * 8];
    }
#pragma unroll
    for (int m = 0; m < 2; m++)
#pragma unroll
      for (int n = 0; n < 4; n++)
        acc[m][n] = __builtin_amdgcn_mfma_f32_16x16x32_bf16(af[m], bfr[n], acc[m][n], 0, 0, 0);
    __syncthreads();
  }
#pragma unroll
  for (int m = 0; m < 2; m++)
#pragma unroll
    for (int n = 0; n < 4; n++)
#pragma unroll
      for (int r = 0; r < 4; r++) {
        int row = brow + wm * 32 + m * 16 + (lane >> 4) * 4 + r;
        int col = bcol + wn * 64 + n * 16 + (lane & 15);
        op[(size_t)row * Cn + col] = acc[m][n][r];
      }
}

// ---------------- per-head V transpose (3 sources via grid.z) ----------------
__global__ void vtrans(const short* __restrict__ s0, const short* __restrict__ s1,
                       const short* __restrict__ s2, short* __restrict__ d0,
                       short* __restrict__ d1, short* __restrict__ d2) {
  __shared__ short tile[64][72];   // pad 8: rows stay 16B-aligned (144B)
  const short* src = blockIdx.z == 0 ? s0 : (blockIdx.z == 1 ? s1 : s2);
  short* dst = blockIdx.z == 0 ? d0 : (blockIdx.z == 1 ? d1 : d2);
  const int tt = blockIdx.x, bh = blockIdx.y;
  const int b = bh / Hn, h = bh % Hn;
  const int tid = threadIdx.x;
#pragma unroll
  for (int i = 0; i < 2; i++) {
    int chunk = i * 256 + tid;            // 512 chunks of 8 elems
    int t = chunk >> 3, c = chunk & 7;
    s16x8 v = *(const s16x8*)(src + (size_t)(b * Tn + tt * 64 + t) * N3 +
                              2 * Cn + h * HDn + c * 8);
    *(s16x8*)&tile[t][c * 8] = v;
  }
  __syncthreads();
#pragma unroll
  for (int i = 0; i < 2; i++) {
    int chunk = i * 256 + tid;
    int d = chunk >> 3, tc = chunk & 7;
    s16x8 v;
#pragma unroll
    for (int j = 0; j < 8; j++) v[j] = tile[tc * 8 + j][d];
    *(s16x8*)(dst + (size_t)bh * (64 * 1024) + (size_t)d * 1024 + tt * 64 + tc * 8) = v;
  }
}

// ---------------- unified flash attention (causal, swapped-QK^T, QBLK=128) --------
// grid (24 bh, 5 combo, 8 j-reversed). Each wave owns TWO 16-row q-groups (u=0,1)
// 64 rows apart: every K/V LDS A-frag read feeds 2 MFMAs. combo 0..3 = (q,k) bound
// pairs (min = P vL, max = P vU since P >= 0); combo 4 = main.
// (256,3): 84 VGPR, no spill (verified R11: 51.4 us). (256,4) SPILLS (R10).
// V must stay LDS-staged: direct per-lane V-frag loads are inter-lane strided 2KB
// -> uncoalesced, 8x FETCH + VGPR spill (R12: 169 us). Do NOT revisit.
__launch_bounds__(256, 3)
__global__ void flash_all(const short* __restrict__ qkv, const short* __restrict__ lowb,
                          const short* __restrict__ upb, const short* __restrict__ vtq,
                          const short* __restrict__ vtl, const short* __restrict__ vtu,
                          short* __restrict__ yab, short* __restrict__ comb) {
  constexpr float SCL = 0.18033688f;       // (1/sqrt(64)) * log2(e)
  constexpr float THR = 8.0f / SCL;        // defer-max threshold, raw-score domain
  __shared__ short Kt[64 * 64];            // 8 KB (source pre-XOR-swizzled)
  __shared__ short Vt0[64 * 64];           // 8 KB
  __shared__ short Vt1[64 * 64];           // 8 KB
  __shared__ short Pt[8 * 16 * 64];        // 16 KB: per (wave,u) 16q x 64k P^T
  const int tid = threadIdx.x, wave = tid >> 6, lane = tid & 63;
  const int g = lane >> 4, q = lane & 15;
  const int bh = blockIdx.x, combo = blockIdx.y;
  const int j = 7 - blockIdx.z;            // long blocks dispatch first
  const int qt0 = j * 128;
  const int b = bh / Hn, h = bh % Hn;
  const bool isMain = (combo == 4);
  const short* Qsrc = isMain ? qkv : ((combo & 2) ? upb : lowb);
  const short* Ksrc = isMain ? qkv : ((combo & 1) ? upb : lowb);
  const short* V0t = isMain ? vtq : vtl;
  const short* V1t = vtu;
  const int qswz = (q & 7) << 4;

  // staging source offsets (lane-dependent, kv-invariant)
  int koff[2], voff[2];
#pragma unroll
  for (int ii = 0; ii < 2; ++ii) {
    int chunk = (wave * 2 + ii) * 64 + lane, row = chunk >> 3, c = chunk & 7;
    int cg = c ^ (row & 7);
    koff[ii] = row * N3 + cg * 8;
    voff[ii] = row * 1024 + cg * 8;
  }
  const short* Kbase = Ksrc + (size_t)(b * Tn) * N3 + Cn + h * HDn;
  const short* V0base = V0t + (size_t)bh * (64 * 1024);
  const short* V1base = V1t + (size_t)bh * (64 * 1024);

  // Q frags (PV-style B-frag): lane holds Q[q][8 contiguous d]
  bf16x8 aq[2][2];
#pragma unroll
  for (int u = 0; u < 2; u++) {
    int trow = qt0 + u * 64 + wave * 16 + q;
    const short* qp = Qsrc + (size_t)(b * Tn + trow) * N3 + h * HDn;
#pragma unroll
    for (int s = 0; s < 2; s++) aq[u][s] = *(const bf16x8*)(qp + s * 32 + g * 8);
  }

  f32x4 o0[2][4], o1[2][4];     // o[u][mf][r]: d = mf*16 + g*4 + r, col q
  float mrow[2], lrow[2];
#pragma unroll
  for (int u = 0; u < 2; u++) {
    mrow[u] = -INFINITY; lrow[u] = 0.f;
#pragma unroll
    for (int n = 0; n < 4; n++) { o0[u][n] = fz(); o1[u][n] = fz(); }
  }

  // softmax for one q-group; sv = S^T fragment (k = m*16+g*4+r, col q)
  auto softmax_u = [&](f32x4 (&sv)[4], int u, auto diagc) {
    constexpr bool DIAG = decltype(diagc)::value;
    if constexpr (DIAG) {
      const int rhs = wave * 16 + q, kb = g * 4;
#pragma unroll
      for (int m = 0; m < 4; m++)
#pragma unroll
        for (int r = 0; r < 4; r++)
          sv[m][r] = (m * 16 + kb + r <= rhs) ? sv[m][r] : -INFINITY;
    }
    float mx = -INFINITY;
#pragma unroll
    for (int m = 0; m < 4; m++)
#pragma unroll
      for (int r = 0; r < 4; r++) mx = fmaxf(mx, sv[m][r]);
    mx = fmaxf(mx, __shfl_xor(mx, 16));
    mx = fmaxf(mx, __shfl_xor(mx, 32));
    if (!__all(mx <= mrow[u] + THR)) {     // defer-max (T13)
      float mnew = fmaxf(mrow[u], mx);
      float corr = fexp2((mrow[u] - mnew) * SCL);
      mrow[u] = mnew; lrow[u] *= corr;
#pragma unroll
      for (int n = 0; n < 4; n++) {
        o0[u][n][0] *= corr; o0[u][n][1] *= corr;
        o0[u][n][2] *= corr; o0[u][n][3] *= corr;
      }
      if (!isMain) {
#pragma unroll
        for (int n = 0; n < 4; n++) {
          o1[u][n][0] *= corr; o1[u][n][1] *= corr;
          o1[u][n][2] *= corr; o1[u][n][3] *= corr;
        }
      }
    }
    const float nms = -mrow[u] * SCL;
    float ps = 0.f;
#pragma unroll
    for (int m = 0; m < 4; m++)
#pragma unroll
      for (int r = 0; r < 4; r++) {
        float p = fexp2(fmaf(sv[m][r], SCL, nms));
        sv[m][r] = p;
        ps += p;
      }
    ps += __shfl_xor(ps, 16);
    ps += __shfl_xor(ps, 32);
    lrow[u] += ps;
    // P^T -> Pt (b64 stores; wave-private, same-wave in-order write->read)
    char* PtW = (char*)Pt + (wave * 2 + u) * 2048;
#pragma unroll
    for (int m = 0; m < 4; m++) {
      u32x2 w;
      w[0] = cvtpk(sv[m][0], sv[m][1]);
      w[1] = cvtpk(sv[m][2], sv[m][3]);
      *(u32x2*)(PtW + ((q * 128 + m * 32 + g * 8) ^ qswz)) = w;
    }
  };

  // one kv tile; M0/M1 per-group mode: 2=full, 1=diag, 0=skip
  auto kv_iter = [&](int kv, auto m0c, auto m1c) {
    constexpr int M0 = decltype(m0c)::value;
    constexpr int M1 = decltype(m1c)::value;
    // stage K/V tiles (pre-swizzled source -> linear LDS; reads XOR back)
#pragma unroll
    for (int ii = 0; ii < 2; ++ii)
      cp16((char*)Kt + (wave * 2 + ii) * 1024, Kbase + (size_t)kv * (64 * N3) + koff[ii]);
#pragma unroll
    for (int ii = 0; ii < 2; ++ii)
      cp16((char*)Vt0 + (wave * 2 + ii) * 1024, V0base + kv * 64 + voff[ii]);
    if (!isMain) {
#pragma unroll
      for (int ii = 0; ii < 2; ++ii)
        cp16((char*)Vt1 + (wave * 2 + ii) * 1024, V1base + kv * 64 + voff[ii]);
    }
    __syncthreads();

    // S^T = K Q^T for both q-groups: one bk read feeds 2 MFMAs
    f32x4 sa0[4], sa1[4];
#pragma unroll
    for (int m = 0; m < 4; m++) { sa0[m] = fz(); sa1[m] = fz(); }
    __builtin_amdgcn_s_setprio(1);
#pragma unroll
    for (int m = 0; m < 4; m++) {
#pragma unroll
      for (int s = 0; s < 2; s++) {
        int krow = m * 16 + q;
        bf16x8 bk = *(const bf16x8*)((char*)Kt +
            krow * 128 + ((g * 16 + s * 64) ^ ((krow & 7) << 4)));
        if constexpr (M0 > 0)
          sa0[m] = __builtin_amdgcn_mfma_f32_16x16x32_bf16(bk, aq[0][s], sa0[m], 0, 0, 0);
        if constexpr (M1 > 0)
          sa1[m] = __builtin_amdgcn_mfma_f32_16x16x32_bf16(bk, aq[1][s], sa1[m], 0, 0, 0);
      }
    }
    __builtin_amdgcn_s_setprio(0);

    if constexpr (M0 > 0) softmax_u(sa0, 0, IntC<(M0 == 1)>{});
    if constexpr (M1 > 0) softmax_u(sa1, 1, IntC<(M1 == 1)>{});

    // O^T += V^T P^T: one V read feeds 2 MFMAs (u=0,1)
    __builtin_amdgcn_s_setprio(1);
#pragma unroll
    for (int kk = 0; kk < 2; kk++) {
      bf16x8 pb0, pb1;
      if constexpr (M0 > 0)
        pb0 = *(const bf16x8*)((char*)Pt + (wave * 2 + 0) * 2048 +
                               ((q * 128 + kk * 64 + g * 16) ^ qswz));
      if constexpr (M1 > 0)
        pb1 = *(const bf16x8*)((char*)Pt + (wave * 2 + 1) * 2048 +
                               ((q * 128 + kk * 64 + g * 16) ^ qswz));
#pragma unroll
      for (int mf = 0; mf < 4; mf++) {
        int drow = mf * 16 + q;
        int boff = drow * 128 + ((g * 16 + kk * 64) ^ ((drow & 7) << 4));
        bf16x8 av0 = *(const bf16x8*)((char*)Vt0 + boff);
        if constexpr (M0 > 0)
          o0[0][mf] = __builtin_amdgcn_mfma_f32_16x16x32_bf16(av0, pb0, o0[0][mf], 0, 0, 0);
        if constexpr (M1 > 0)
          o0[1][mf] = __builtin_amdgcn_mfma_f32_16x16x32_bf16(av0, pb1, o0[1][mf], 0, 0, 0);
        if (!isMain) {
          bf16x8 av1 = *(const bf16x8*)((char*)Vt1 + boff);
          if constexpr (M0 > 0)
            o1[0][mf] = __builtin_amdgcn_mfma_f32_16x16x32_bf16(av1, pb0, o1[0][mf], 0, 0, 0);
          if constexpr (M1 > 0)
            o1[1][mf] = __builtin_amdgcn_mfma_f32_16x16x32_bf16(av1, pb1, o1[1][mf], 0, 0, 0);
        }
      }
    }
    __builtin_amdgcn_s_setprio(0);
    __syncthreads();
  };

  const int jj = 2 * j;                    // diag tile of group 0
  for (int kv = 0; kv < jj; ++kv) kv_iter(kv, IntC<2>{}, IntC<2>{});
  kv_iter(jj, IntC<1>{}, IntC<2>{});
  kv_iter(jj + 1, IntC<0>{}, IntC<1>{});

  // epilogue: lane owns row q of group u; packed 8B stores
#pragma unroll
  for (int u = 0; u < 2; u++) {
    const float inv = 1.0f / lrow[u];
    const int trow = qt0 + u * 64 + wave * 16 + q;
    const size_t rowbase = (size_t)(b * Tn + trow) * Cn + h * HDn + g * 4;
#pragma unroll
    for (int mf = 0; mf < 4; mf++) {
      size_t idx = rowbase + mf * 16;
      u32x2 v0;
      v0[0] = cvtpk(o0[u][mf][0] * inv, o0[u][mf][1] * inv);
      v0[1] = cvtpk(o0[u][mf][2] * inv, o0[u][mf][3] * inv);
      if (isMain) {
        *(u32x2*)(yab + idx) = v0;
      } else {
        u32x2 v1;
        v1[0] = cvtpk(o1[u][mf][0] * inv, o1[u][mf][1] * inv);
        v1[1] = cvtpk(o1[u][mf][2] * inv, o1[u][mf][3] * inv);
        // P >= 0 and vL <= vU  =>  P vL <= P vU elementwise
        *(u32x2*)(comb + (size_t)(2 * combo) * SZy + idx) = v0;
        *(u32x2*)(comb + (size_t)(2 * combo + 1) * SZy + idx) = v1;
      }
    }
  }
}

// ---------------- min/max reduce over the 4 bound combos ----------------
__global__ void reduce_minmax(const short* __restrict__ comb, short* __restrict__ ymn,
                              short* __restrict__ ymx) {
  int i = blockIdx.x * 256 + threadIdx.x;   // 8 elems/thread; grid = SZy/8/256 = 768
  s16x8 mn8 = ((const s16x8*)(comb + 0 * SZy))[i];
  s16x8 mx8 = ((const s16x8*)(comb + 1 * SZy))[i];
#pragma unroll
  for (int c = 1; c < 4; c++) {
    s16x8 a = ((const s16x8*)(comb + (size_t)(2 * c) * SZy))[i];
    s16x8 b2 = ((const s16x8*)(comb + (size_t)(2 * c + 1) * SZy))[i];
#pragma unroll
    for (int j = 0; j < 8; j++) {
      mn8[j] = f2bf(fminf(bf2f(mn8[j]), bf2f(a[j])));
      mx8[j] = f2bf(fmaxf(bf2f(mx8[j]), bf2f(b2[j])));
    }
  }
  ((s16x8*)ymn)[i] = mn8;
  ((s16x8*)ymx)[i] = mx8;
}

// ---------------- launch ----------------
extern "C" void kernel_launch(void* const* d_in, const int* in_sizes, int n_in,
                              void* d_out, int out_size, void* d_ws, size_t ws_size,
                              hipStream_t stream) {
  const float* x  = (const float*)d_in[0];
  const float* xl = (const float*)d_in[1];
  const float* xu = (const float*)d_in[2];
  const float* Wa = (const float*)d_in[3];
  const float* Wp = (const float*)d_in[4];
  float* out = (float*)d_out;

  char* p = (char*)d_ws;
  auto carve = [&](size_t bytes) -> char* {
    char* r = p; p += (bytes + 255) & ~(size_t)255; return r;
  };
  short* xb   = (short*)carve((size_t)Mrows * Cn * 2);
  short* midb = (short*)carve((size_t)Mrows * Cn * 2);
  short* radb = (short*)carve((size_t)Mrows * Cn * 2);
  short* wb   = (short*)carve((size_t)N3 * Cn * 2);
  short* awb  = (short*)carve((size_t)N3 * Cn * 2);
  short* wpb  = (short*)carve((size_t)Cn * Cn * 2);
  short* qkvb = (short*)carve((size_t)Mrows * N3 * 2);
  short* lowb = (short*)carve((size_t)Mrows * N3 * 2);
  short* upb  = (short*)carve((size_t)Mrows * N3 * 2);
  short* vtq  = (short*)carve((size_t)24 * 64 * 1024 * 2);
  short* vtl  = (short*)carve((size_t)24 * 64 * 1024 * 2);
  short* vtu  = (short*)carve((size_t)24 * 64 * 1024 * 2);
  short* yab  = (short*)carve(SZy * 2);
  short* ymnb = (short*)carve(SZy * 2);
  short* ymxb = (short*)carve(SZy * 2);
  short* comb = (short*)carve(8 * SZy * 2);

  // bf16 conversions (+ mid/rad, |W|) — W_attn and W_proj merged in one launch
  prep_x<<<1536, 256, 0, stream>>>(x, xl, xu, xb, midb, radb);
  prep_wall<<<2304, 256, 0, stream>>>(Wa, Wp, wb, awb, wpb);

  // qkv / lower / upper, grid.z-split for dispatch width (1152 blocks)
  gemm_qkv3<<<dim3(32, 18, 2), 256, 0, stream>>>(xb, midb, radb, wb, awb,
                                                 qkvb, lowb, upb);

  // per-head V transposes (3 sources, one launch)
  vtrans<<<dim3(16, 24, 3), 256, 0, stream>>>(qkvb, lowb, upb, vtq, vtl, vtu);

  // all 5 attention passes in one launch (QBLK=128) — R11-exact
  flash_all<<<dim3(24, 5, 8), 256, 0, stream>>>(qkvb, lowb, upb, vtq, vtl, vtu,
                                                yab, comb);

  // fold the 4 bound combos into ymin/ymax
  reduce_minmax<<<768, 256, 0, stream>>>(comb, ymnb, ymxb);

  // output projections -> d_out (y, y_lower, y_upper) in one launch
  gemm_proj<<<dim3(32, 6, 3), 256, 0, stream>>>(yab, ymnb, ymxb, wpb, out);
}

// Round 14
// 128.486 us; speedup vs baseline: 1.8763x; 1.0582x over previous
//
#include <hip/hip_runtime.h>
#include <stdint.h>
#include <math.h>

// ---------------- types / helpers ----------------
typedef __attribute__((ext_vector_type(8))) short bf16x8;
typedef __attribute__((ext_vector_type(4))) short s16x4;
typedef __attribute__((ext_vector_type(8))) short s16x8;
typedef __attribute__((ext_vector_type(4))) float f32x4;
typedef __attribute__((ext_vector_type(2))) uint32_t u32x2;

#define DEVI __device__ __forceinline__

constexpr int Bn = 2, Tn = 1024, Cn = 768, Hn = 12, HDn = 64;
constexpr int N3 = 3 * Cn;          // 2304
constexpr int Mrows = Bn * Tn;      // 2048
constexpr size_t SZy = (size_t)Mrows * Cn;  // elems per [B,T,C] slice

template <int V> struct IntC { static constexpr int value = V; };

DEVI short f2bf(float f) {
  union { float f; uint32_t u; } v; v.f = f;
  uint32_t u = v.u;
  return (short)((u + 0x7FFFu + ((u >> 16) & 1u)) >> 16);  // RNE
}
DEVI float bf2f(short b) {
  union { uint32_t u; float f; } v; v.u = ((uint32_t)(uint16_t)b) << 16;
  return v.f;
}
DEVI float fexp2(float x) { return __builtin_exp2f(x); }
// pack two f32 -> two bf16 in one u32 (RNE), single HW instr (T12)
DEVI uint32_t cvtpk(float lo, float hi) {
  uint32_t r;
  asm("v_cvt_pk_bf16_f32 %0, %1, %2" : "=v"(r) : "v"(lo), "v"(hi));
  return r;
}
// async global->LDS, 16B per lane. LDS dest = wave-uniform base + lane*16 (linear);
// global src is per-lane (pre-swizzle the source when a swizzled layout is wanted).
DEVI void cp16(void* lds, const void* g) {
  __builtin_amdgcn_global_load_lds(
      (const __attribute__((address_space(1))) uint32_t*)(uintptr_t)g,
      (__attribute__((address_space(3))) uint32_t*)(uint32_t)(uintptr_t)lds,
      16, 0, 0);
}
DEVI f32x4 fz() { f32x4 z; z[0] = 0.f; z[1] = 0.f; z[2] = 0.f; z[3] = 0.f; return z; }

// ---------------- merged prep kernel (fp32 -> bf16) ----------------
// blocks [0,1536):   x/xl/xu -> xb, mid, rad
// blocks [1536,3264): W_attn -> wb, |W| -> awb
// blocks [3264,3840): W_proj -> wpb
__global__ void prep_all(const float* __restrict__ x, const float* __restrict__ xl,
                         const float* __restrict__ xu, const float* __restrict__ Wa,
                         const float* __restrict__ Wp, short* __restrict__ xb,
                         short* __restrict__ mb, short* __restrict__ rb,
                         short* __restrict__ wb, short* __restrict__ awb,
                         short* __restrict__ wpb) {
  const int bid = blockIdx.x;
  if (bid < 1536) {
    int i = bid * 256 + threadIdx.x;
    float4 vx = ((const float4*)x)[i];
    float4 vl = ((const float4*)xl)[i];
    float4 vu = ((const float4*)xu)[i];
    s16x4 a, m_, g;
    a[0] = f2bf(vx.x); a[1] = f2bf(vx.y); a[2] = f2bf(vx.z); a[3] = f2bf(vx.w);
    m_[0] = f2bf(0.5f * (vl.x + vu.x)); m_[1] = f2bf(0.5f * (vl.y + vu.y));
    m_[2] = f2bf(0.5f * (vl.z + vu.z)); m_[3] = f2bf(0.5f * (vl.w + vu.w));
    g[0] = f2bf(0.5f * (vu.x - vl.x)); g[1] = f2bf(0.5f * (vu.y - vl.y));
    g[2] = f2bf(0.5f * (vu.z - vl.z)); g[3] = f2bf(0.5f * (vu.w - vl.w));
    ((s16x4*)xb)[i] = a; ((s16x4*)mb)[i] = m_; ((s16x4*)rb)[i] = g;
  } else if (bid < 3264) {
    int i = (bid - 1536) * 256 + threadIdx.x;
    float4 v = ((const float4*)Wa)[i];
    s16x4 a, b2;
    a[0] = f2bf(v.x); a[1] = f2bf(v.y); a[2] = f2bf(v.z); a[3] = f2bf(v.w);
    b2[0] = f2bf(fabsf(v.x)); b2[1] = f2bf(fabsf(v.y));
    b2[2] = f2bf(fabsf(v.z)); b2[3] = f2bf(fabsf(v.w));
    ((s16x4*)wb)[i] = a; ((s16x4*)awb)[i] = b2;
  } else {
    int i = (bid - 3264) * 256 + threadIdx.x;
    float4 v = ((const float4*)Wp)[i];
    s16x4 a;
    a[0] = f2bf(v.x); a[1] = f2bf(v.y); a[2] = f2bf(v.z); a[3] = f2bf(v.w);
    ((s16x4*)wpb)[i] = a;
  }
}

// ---------------- fused input GEMM: qkv / lower / upper in one launch ----------------
// acc0 = x @ W^T ; acc1 = mid @ W^T ; acc2 = rad @ |W|^T
// qkv = acc0 ; low = acc1 - acc2 ; up = acc1 + acc2
// BM=64, BN=128, wave-tile 32x64, grid(32, 18).  (R11-verified: ~43us, no spill)
// (256,3): 170-VGPR budget. (256,4) caps at 128 and SPILLS (R9: 295 MB scratch).
// grid.z split tested R13: REGRESSED (+6us, W re-read doubles FETCH). Keep fused.
__launch_bounds__(256, 3)
__global__ void gemm_qkv3(const short* __restrict__ A0, const short* __restrict__ A1,
                          const short* __restrict__ A2, const short* __restrict__ B0,
                          const short* __restrict__ B1, short* __restrict__ qkv,
                          short* __restrict__ low, short* __restrict__ up) {
  constexpr int BM = 64, BN = 128;
  __shared__ short At[3 * BM * 32];   // 12 KB
  __shared__ short Bt[2 * BN * 32];   // 16 KB
  const int tid = threadIdx.x, wave = tid >> 6, lane = tid & 63;
  const int g = lane >> 4, q = lane & 15;
  const int wm = wave >> 1, wn = wave & 1;
  const int brow = blockIdx.x * BM, bcol = blockIdx.y * BN;
  const short* As[3] = {A0, A1, A2};
  const short* Bs[2] = {B0, B1};

  f32x4 acc[3][2][4];
#pragma unroll
  for (int a = 0; a < 3; a++)
#pragma unroll
    for (int m = 0; m < 2; m++)
#pragma unroll
      for (int n = 0; n < 4; n++) acc[a][m][n] = fz();

  const int arow = tid >> 2, ac = tid & 3;           // A: 1 chunk/thread per tile
  for (int kt = 0; kt < Cn / 32; ++kt) {
#pragma unroll
    for (int a = 0; a < 3; a++)
      cp16((char*)At + a * 4096 + tid * 16,
           As[a] + (size_t)(brow + arow) * Cn + (kt * 32 + ac * 8));
#pragma unroll
    for (int b2 = 0; b2 < 2; b2++)
#pragma unroll
      for (int ii = 0; ii < 2; ++ii) {               // B: 128x32 tile, 2/thread
        int i = wave * 2 + ii;
        int ch = i * 64 + lane, row = ch >> 2, c = ch & 3;
        cp16((char*)Bt + b2 * 8192 + i * 1024,
             Bs[b2] + (size_t)(bcol + row) * Cn + (kt * 32 + c * 8));
      }
    __syncthreads();
    bf16x8 bfr[2][4];
#pragma unroll
    for (int b2 = 0; b2 < 2; b2++)
#pragma unroll
      for (int n = 0; n < 4; n++) {
        int r = wn * 64 + n * 16 + q;
        bfr[b2][n] = *(const bf16x8*)&Bt[b2 * (BN * 32) + r * 32 + g * 8];
      }
#pragma unroll
    for (int a = 0; a < 3; a++) {
      bf16x8 af[2];
#pragma unroll
      for (int m = 0; m < 2; m++) {
        int r = wm * 32 + m * 16 + q;
        af[m] = *(const bf16x8*)&At[a * (BM * 32) + r * 32 + g * 8];
      }
      const int bs = (a == 2) ? 1 : 0;
#pragma unroll
      for (int m = 0; m < 2; m++)
#pragma unroll
        for (int n = 0; n < 4; n++)
          acc[a][m][n] = __builtin_amdgcn_mfma_f32_16x16x32_bf16(
              af[m], bfr[bs][n], acc[a][m][n], 0, 0, 0);
    }
    __syncthreads();
  }
#pragma unroll
  for (int m = 0; m < 2; m++)
#pragma unroll
    for (int n = 0; n < 4; n++)
#pragma unroll
      for (int r = 0; r < 4; r++) {
        int row = brow + wm * 32 + m * 16 + g * 4 + r;
        int col = bcol + wn * 64 + n * 16 + q;
        size_t idx = (size_t)row * N3 + col;
        float v0 = acc[0][m][n][r], v1 = acc[1][m][n][r], v2 = acc[2][m][n][r];
        qkv[idx] = f2bf(v0);
        low[idx] = f2bf(v1 - v2);
        up[idx]  = f2bf(v1 + v2);
      }
}

// ---------------- projection GEMM: 3 outputs in one launch (grid.z selects A) -------
// BM=64, BN=128, grid(32, 6, 3)  (known-good (256,4): low VGPR kernel, no spill)
__launch_bounds__(256, 4)
__global__ void gemm_proj(const short* __restrict__ A0, const short* __restrict__ A1,
                          const short* __restrict__ A2, const short* __restrict__ Bw,
                          float* __restrict__ out) {
  constexpr int BM = 64, BN = 128;
  __shared__ short At[BM * 32];
  __shared__ short Bt[BN * 32];
  const short* Ap = blockIdx.z == 0 ? A0 : (blockIdx.z == 1 ? A1 : A2);
  float* op = out + (size_t)blockIdx.z * SZy;
  const int tid = threadIdx.x, wave = tid >> 6, lane = tid & 63;
  const int wm = wave >> 1, wn = wave & 1;
  const int brow = blockIdx.x * BM, bcol = blockIdx.y * BN;

  f32x4 acc[2][4];
#pragma unroll
  for (int m = 0; m < 2; m++)
#pragma unroll
    for (int n = 0; n < 4; n++) acc[m][n] = fz();

  const int chunk = wave * 64 + lane, srow = chunk >> 2, sc = chunk & 3;
  for (int kt = 0; kt < Cn / 32; ++kt) {
    cp16((char*)At + wave * 1024, Ap + (size_t)(brow + srow) * Cn + (kt * 32 + sc * 8));
#pragma unroll
    for (int ii = 0; ii < 2; ++ii) {
      int i = wave * 2 + ii;
      int ch = i * 64 + lane, row = ch >> 2, c = ch & 3;
      cp16((char*)Bt + i * 1024, Bw + (size_t)(bcol + row) * Cn + (kt * 32 + c * 8));
    }
    __syncthreads();
    bf16x8 af[2], bfr[4];
#pragma unroll
    for (int m = 0; m < 2; m++) {
      int r = wm * 32 + m * 16 + (lane & 15);
      af[m] = *(const bf16x8*)&At[r * 32 + (lane >> 4) * 8];
    }
#pragma unroll
    for (int n = 0; n < 4; n++) {
      int r = wn * 64 + n * 16 + (lane & 15);
      bfr[n] = *(const bf16x8*)&Bt[r * 32 + (lane >> 4) * 8];
    }
#pragma unroll
    for (int m = 0; m < 2; m++)
#pragma unroll
      for (int n = 0; n < 4; n++)
        acc[m][n] = __builtin_amdgcn_mfma_f32_16x16x32_bf16(af[m], bfr[n], acc[m][n], 0, 0, 0);
    __syncthreads();
  }
#pragma unroll
  for (int m = 0; m < 2; m++)
#pragma unroll
    for (int n = 0; n < 4; n++)
#pragma unroll
      for (int r = 0; r < 4; r++) {
        int row = brow + wm * 32 + m * 16 + (lane >> 4) * 4 + r;
        int col = bcol + wn * 64 + n * 16 + (lane & 15);
        op[(size_t)row * Cn + col] = acc[m][n][r];
      }
}

// ---------------- per-head V transpose (3 sources via grid.z) ----------------
__global__ void vtrans(const short* __restrict__ s0, const short* __restrict__ s1,
                       const short* __restrict__ s2, short* __restrict__ d0,
                       short* __restrict__ d1, short* __restrict__ d2) {
  __shared__ short tile[64][72];   // pad 8: rows stay 16B-aligned (144B)
  const short* src = blockIdx.z == 0 ? s0 : (blockIdx.z == 1 ? s1 : s2);
  short* dst = blockIdx.z == 0 ? d0 : (blockIdx.z == 1 ? d1 : d2);
  const int tt = blockIdx.x, bh = blockIdx.y;
  const int b = bh / Hn, h = bh % Hn;
  const int tid = threadIdx.x;
#pragma unroll
  for (int i = 0; i < 2; i++) {
    int chunk = i * 256 + tid;            // 512 chunks of 8 elems
    int t = chunk >> 3, c = chunk & 7;
    s16x8 v = *(const s16x8*)(src + (size_t)(b * Tn + tt * 64 + t) * N3 +
                              2 * Cn + h * HDn + c * 8);
    *(s16x8*)&tile[t][c * 8] = v;
  }
  __syncthreads();
#pragma unroll
  for (int i = 0; i < 2; i++) {
    int chunk = i * 256 + tid;
    int d = chunk >> 3, tc = chunk & 7;
    s16x8 v;
#pragma unroll
    for (int j = 0; j < 8; j++) v[j] = tile[tc * 8 + j][d];
    *(s16x8*)(dst + (size_t)bh * (64 * 1024) + (size_t)d * 1024 + tt * 64 + tc * 8) = v;
  }
}

// ---------------- unified flash attention (causal, swapped-QK^T, QBLK=128) --------
// grid (24 bh, 5 combo, 8 j-reversed). Each wave owns TWO 16-row q-groups (u=0,1)
// 64 rows apart: every K/V LDS A-frag read feeds 2 MFMAs. combo 0..3 = (q,k) bound
// pairs (min = P vL, max = P vU since P >= 0); combo 4 = main.
// (256,3): 84 VGPR, no spill (verified R11: 51.4 us). (256,4) SPILLS (R10).
// V must stay LDS-staged: direct per-lane V-frag loads are inter-lane strided 2KB
// -> uncoalesced, 8x FETCH + spill (R12: 169 us). Dbuf/counted-vmcnt: neutral (R7).
__launch_bounds__(256, 3)
__global__ void flash_all(const short* __restrict__ qkv, const short* __restrict__ lowb,
                          const short* __restrict__ upb, const short* __restrict__ vtq,
                          const short* __restrict__ vtl, const short* __restrict__ vtu,
                          short* __restrict__ yab, short* __restrict__ comb) {
  constexpr float SCL = 0.18033688f;       // (1/sqrt(64)) * log2(e)
  constexpr float THR = 8.0f / SCL;        // defer-max threshold, raw-score domain
  __shared__ short Kt[64 * 64];            // 8 KB (source pre-XOR-swizzled)
  __shared__ short Vt0[64 * 64];           // 8 KB
  __shared__ short Vt1[64 * 64];           // 8 KB
  __shared__ short Pt[8 * 16 * 64];        // 16 KB: per (wave,u) 16q x 64k P^T
  const int tid = threadIdx.x, wave = tid >> 6, lane = tid & 63;
  const int g = lane >> 4, q = lane & 15;
  const int bh = blockIdx.x, combo = blockIdx.y;
  const int j = 7 - blockIdx.z;            // long blocks dispatch first
  const int qt0 = j * 128;
  const int b = bh / Hn, h = bh % Hn;
  const bool isMain = (combo == 4);
  const short* Qsrc = isMain ? qkv : ((combo & 2) ? upb : lowb);
  const short* Ksrc = isMain ? qkv : ((combo & 1) ? upb : lowb);
  const short* V0t = isMain ? vtq : vtl;
  const short* V1t = vtu;
  const int qswz = (q & 7) << 4;

  // staging source offsets (lane-dependent, kv-invariant)
  int koff[2], voff[2];
#pragma unroll
  for (int ii = 0; ii < 2; ++ii) {
    int chunk = (wave * 2 + ii) * 64 + lane, row = chunk >> 3, c = chunk & 7;
    int cg = c ^ (row & 7);
    koff[ii] = row * N3 + cg * 8;
    voff[ii] = row * 1024 + cg * 8;
  }
  const short* Kbase = Ksrc + (size_t)(b * Tn) * N3 + Cn + h * HDn;
  const short* V0base = V0t + (size_t)bh * (64 * 1024);
  const short* V1base = V1t + (size_t)bh * (64 * 1024);

  // Q frags (PV-style B-frag): lane holds Q[q][8 contiguous d]
  bf16x8 aq[2][2];
#pragma unroll
  for (int u = 0; u < 2; u++) {
    int trow = qt0 + u * 64 + wave * 16 + q;
    const short* qp = Qsrc + (size_t)(b * Tn + trow) * N3 + h * HDn;
#pragma unroll
    for (int s = 0; s < 2; s++) aq[u][s] = *(const bf16x8*)(qp + s * 32 + g * 8);
  }

  f32x4 o0[2][4], o1[2][4];     // o[u][mf][r]: d = mf*16 + g*4 + r, col q
  float mrow[2], lrow[2];
#pragma unroll
  for (int u = 0; u < 2; u++) {
    mrow[u] = -INFINITY; lrow[u] = 0.f;
#pragma unroll
    for (int n = 0; n < 4; n++) { o0[u][n] = fz(); o1[u][n] = fz(); }
  }

  // softmax for one q-group; sv = S^T fragment (k = m*16+g*4+r, col q)
  auto softmax_u = [&](f32x4 (&sv)[4], int u, auto diagc) {
    constexpr bool DIAG = decltype(diagc)::value;
    if constexpr (DIAG) {
      const int rhs = wave * 16 + q, kb = g * 4;
#pragma unroll
      for (int m = 0; m < 4; m++)
#pragma unroll
        for (int r = 0; r < 4; r++)
          sv[m][r] = (m * 16 + kb + r <= rhs) ? sv[m][r] : -INFINITY;
    }
    float mx = -INFINITY;
#pragma unroll
    for (int m = 0; m < 4; m++)
#pragma unroll
      for (int r = 0; r < 4; r++) mx = fmaxf(mx, sv[m][r]);
    mx = fmaxf(mx, __shfl_xor(mx, 16));
    mx = fmaxf(mx, __shfl_xor(mx, 32));
    if (!__all(mx <= mrow[u] + THR)) {     // defer-max (T13)
      float mnew = fmaxf(mrow[u], mx);
      float corr = fexp2((mrow[u] - mnew) * SCL);
      mrow[u] = mnew; lrow[u] *= corr;
#pragma unroll
      for (int n = 0; n < 4; n++) {
        o0[u][n][0] *= corr; o0[u][n][1] *= corr;
        o0[u][n][2] *= corr; o0[u][n][3] *= corr;
      }
      if (!isMain) {
#pragma unroll
        for (int n = 0; n < 4; n++) {
          o1[u][n][0] *= corr; o1[u][n][1] *= corr;
          o1[u][n][2] *= corr; o1[u][n][3] *= corr;
        }
      }
    }
    const float nms = -mrow[u] * SCL;
    float ps = 0.f;
#pragma unroll
    for (int m = 0; m < 4; m++)
#pragma unroll
      for (int r = 0; r < 4; r++) {
        float p = fexp2(fmaf(sv[m][r], SCL, nms));
        sv[m][r] = p;
        ps += p;
      }
    ps += __shfl_xor(ps, 16);
    ps += __shfl_xor(ps, 32);
    lrow[u] += ps;
    // P^T -> Pt (b64 stores; wave-private, same-wave in-order write->read)
    char* PtW = (char*)Pt + (wave * 2 + u) * 2048;
#pragma unroll
    for (int m = 0; m < 4; m++) {
      u32x2 w;
      w[0] = cvtpk(sv[m][0], sv[m][1]);
      w[1] = cvtpk(sv[m][2], sv[m][3]);
      *(u32x2*)(PtW + ((q * 128 + m * 32 + g * 8) ^ qswz)) = w;
    }
  };

  // one kv tile; M0/M1 per-group mode: 2=full, 1=diag, 0=skip
  auto kv_iter = [&](int kv, auto m0c, auto m1c) {
    constexpr int M0 = decltype(m0c)::value;
    constexpr int M1 = decltype(m1c)::value;
    // stage K/V tiles (pre-swizzled source -> linear LDS; reads XOR back)
#pragma unroll
    for (int ii = 0; ii < 2; ++ii)
      cp16((char*)Kt + (wave * 2 + ii) * 1024, Kbase + (size_t)kv * (64 * N3) + koff[ii]);
#pragma unroll
    for (int ii = 0; ii < 2; ++ii)
      cp16((char*)Vt0 + (wave * 2 + ii) * 1024, V0base + kv * 64 + voff[ii]);
    if (!isMain) {
#pragma unroll
      for (int ii = 0; ii < 2; ++ii)
        cp16((char*)Vt1 + (wave * 2 + ii) * 1024, V1base + kv * 64 + voff[ii]);
    }
    __syncthreads();

    // S^T = K Q^T for both q-groups: one bk read feeds 2 MFMAs
    f32x4 sa0[4], sa1[4];
#pragma unroll
    for (int m = 0; m < 4; m++) { sa0[m] = fz(); sa1[m] = fz(); }
    __builtin_amdgcn_s_setprio(1);
#pragma unroll
    for (int m = 0; m < 4; m++) {
#pragma unroll
      for (int s = 0; s < 2; s++) {
        int krow = m * 16 + q;
        bf16x8 bk = *(const bf16x8*)((char*)Kt +
            krow * 128 + ((g * 16 + s * 64) ^ ((krow & 7) << 4)));
        if constexpr (M0 > 0)
          sa0[m] = __builtin_amdgcn_mfma_f32_16x16x32_bf16(bk, aq[0][s], sa0[m], 0, 0, 0);
        if constexpr (M1 > 0)
          sa1[m] = __builtin_amdgcn_mfma_f32_16x16x32_bf16(bk, aq[1][s], sa1[m], 0, 0, 0);
      }
    }
    __builtin_amdgcn_s_setprio(0);

    if constexpr (M0 > 0) softmax_u(sa0, 0, IntC<(M0 == 1)>{});
    if constexpr (M1 > 0) softmax_u(sa1, 1, IntC<(M1 == 1)>{});

    // O^T += V^T P^T: one V read feeds 2 MFMAs (u=0,1)
    __builtin_amdgcn_s_setprio(1);
#pragma unroll
    for (int kk = 0; kk < 2; kk++) {
      bf16x8 pb0, pb1;
      if constexpr (M0 > 0)
        pb0 = *(const bf16x8*)((char*)Pt + (wave * 2 + 0) * 2048 +
                               ((q * 128 + kk * 64 + g * 16) ^ qswz));
      if constexpr (M1 > 0)
        pb1 = *(const bf16x8*)((char*)Pt + (wave * 2 + 1) * 2048 +
                               ((q * 128 + kk * 64 + g * 16) ^ qswz));
#pragma unroll
      for (int mf = 0; mf < 4; mf++) {
        int drow = mf * 16 + q;
        int boff = drow * 128 + ((g * 16 + kk * 64) ^ ((drow & 7) << 4));
        bf16x8 av0 = *(const bf16x8*)((char*)Vt0 + boff);
        if constexpr (M0 > 0)
          o0[0][mf] = __builtin_amdgcn_mfma_f32_16x16x32_bf16(av0, pb0, o0[0][mf], 0, 0, 0);
        if constexpr (M1 > 0)
          o0[1][mf] = __builtin_amdgcn_mfma_f32_16x16x32_bf16(av0, pb1, o0[1][mf], 0, 0, 0);
        if (!isMain) {
          bf16x8 av1 = *(const bf16x8*)((char*)Vt1 + boff);
          if constexpr (M0 > 0)
            o1[0][mf] = __builtin_amdgcn_mfma_f32_16x16x32_bf16(av1, pb0, o1[0][mf], 0, 0, 0);
          if constexpr (M1 > 0)
            o1[1][mf] = __builtin_amdgcn_mfma_f32_16x16x32_bf16(av1, pb1, o1[1][mf], 0, 0, 0);
        }
      }
    }
    __builtin_amdgcn_s_setprio(0);
    __syncthreads();
  };

  const int jj = 2 * j;                    // diag tile of group 0
  for (int kv = 0; kv < jj; ++kv) kv_iter(kv, IntC<2>{}, IntC<2>{});
  kv_iter(jj, IntC<1>{}, IntC<2>{});
  kv_iter(jj + 1, IntC<0>{}, IntC<1>{});

  // epilogue: lane owns row q of group u; packed 8B stores
#pragma unroll
  for (int u = 0; u < 2; u++) {
    const float inv = 1.0f / lrow[u];
    const int trow = qt0 + u * 64 + wave * 16 + q;
    const size_t rowbase = (size_t)(b * Tn + trow) * Cn + h * HDn + g * 4;
#pragma unroll
    for (int mf = 0; mf < 4; mf++) {
      size_t idx = rowbase + mf * 16;
      u32x2 v0;
      v0[0] = cvtpk(o0[u][mf][0] * inv, o0[u][mf][1] * inv);
      v0[1] = cvtpk(o0[u][mf][2] * inv, o0[u][mf][3] * inv);
      if (isMain) {
        *(u32x2*)(yab + idx) = v0;
      } else {
        u32x2 v1;
        v1[0] = cvtpk(o1[u][mf][0] * inv, o1[u][mf][1] * inv);
        v1[1] = cvtpk(o1[u][mf][2] * inv, o1[u][mf][3] * inv);
        // P >= 0 and vL <= vU  =>  P vL <= P vU elementwise
        *(u32x2*)(comb + (size_t)(2 * combo) * SZy + idx) = v0;
        *(u32x2*)(comb + (size_t)(2 * combo + 1) * SZy + idx) = v1;
      }
    }
  }
}

// ---------------- min/max reduce over the 4 bound combos ----------------
__global__ void reduce_minmax(const short* __restrict__ comb, short* __restrict__ ymn,
                              short* __restrict__ ymx) {
  int i = blockIdx.x * 256 + threadIdx.x;   // 8 elems/thread; grid = SZy/8/256 = 768
  s16x8 mn8 = ((const s16x8*)(comb + 0 * SZy))[i];
  s16x8 mx8 = ((const s16x8*)(comb + 1 * SZy))[i];
#pragma unroll
  for (int c = 1; c < 4; c++) {
    s16x8 a = ((const s16x8*)(comb + (size_t)(2 * c) * SZy))[i];
    s16x8 b2 = ((const s16x8*)(comb + (size_t)(2 * c + 1) * SZy))[i];
#pragma unroll
    for (int j = 0; j < 8; j++) {
      mn8[j] = f2bf(fminf(bf2f(mn8[j]), bf2f(a[j])));
      mx8[j] = f2bf(fmaxf(bf2f(mx8[j]), bf2f(b2[j])));
    }
  }
  ((s16x8*)ymn)[i] = mn8;
  ((s16x8*)ymx)[i] = mx8;
}

// ---------------- launch ----------------
extern "C" void kernel_launch(void* const* d_in, const int* in_sizes, int n_in,
                              void* d_out, int out_size, void* d_ws, size_t ws_size,
                              hipStream_t stream) {
  const float* x  = (const float*)d_in[0];
  const float* xl = (const float*)d_in[1];
  const float* xu = (const float*)d_in[2];
  const float* Wa = (const float*)d_in[3];
  const float* Wp = (const float*)d_in[4];
  float* out = (float*)d_out;

  char* p = (char*)d_ws;
  auto carve = [&](size_t bytes) -> char* {
    char* r = p; p += (bytes + 255) & ~(size_t)255; return r;
  };
  short* xb   = (short*)carve((size_t)Mrows * Cn * 2);
  short* midb = (short*)carve((size_t)Mrows * Cn * 2);
  short* radb = (short*)carve((size_t)Mrows * Cn * 2);
  short* wb   = (short*)carve((size_t)N3 * Cn * 2);
  short* awb  = (short*)carve((size_t)N3 * Cn * 2);
  short* wpb  = (short*)carve((size_t)Cn * Cn * 2);
  short* qkvb = (short*)carve((size_t)Mrows * N3 * 2);
  short* lowb = (short*)carve((size_t)Mrows * N3 * 2);
  short* upb  = (short*)carve((size_t)Mrows * N3 * 2);
  short* vtq  = (short*)carve((size_t)24 * 64 * 1024 * 2);
  short* vtl  = (short*)carve((size_t)24 * 64 * 1024 * 2);
  short* vtu  = (short*)carve((size_t)24 * 64 * 1024 * 2);
  short* yab  = (short*)carve(SZy * 2);
  short* ymnb = (short*)carve(SZy * 2);
  short* ymxb = (short*)carve(SZy * 2);
  short* comb = (short*)carve(8 * SZy * 2);

  // all bf16 conversions (+ mid/rad, |W|) in ONE launch
  prep_all<<<3840, 256, 0, stream>>>(x, xl, xu, Wa, Wp, xb, midb, radb,
                                     wb, awb, wpb);

  // qkv / lower / upper in one fused launch (R11-verified form)
  gemm_qkv3<<<dim3(32, 18), 256, 0, stream>>>(xb, midb, radb, wb, awb,
                                              qkvb, lowb, upb);

  // per-head V transposes (3 sources, one launch)
  vtrans<<<dim3(16, 24, 3), 256, 0, stream>>>(qkvb, lowb, upb, vtq, vtl, vtu);

  // all 5 attention passes in one launch (QBLK=128) — R11-exact
  flash_all<<<dim3(24, 5, 8), 256, 0, stream>>>(qkvb, lowb, upb, vtq, vtl, vtu,
                                                yab, comb);

  // fold the 4 bound combos into ymin/ymax
  reduce_minmax<<<768, 256, 0, stream>>>(comb, ymnb, ymxb);

  // output projections -> d_out (y, y_lower, y_upper) in one launch
  gemm_proj<<<dim3(32, 6, 3), 256, 0, stream>>>(yab, ymnb, ymxb, wpb, out);
}

// Round 15
// 128.334 us; speedup vs baseline: 1.8785x; 1.0012x over previous
//
#include <hip/hip_runtime.h>
#include <stdint.h>
#include <math.h>

// ---------------- types / helpers ----------------
typedef __attribute__((ext_vector_type(8))) short bf16x8;
typedef __attribute__((ext_vector_type(4))) short s16x4;
typedef __attribute__((ext_vector_type(8))) short s16x8;
typedef __attribute__((ext_vector_type(4))) float f32x4;
typedef __attribute__((ext_vector_type(2))) uint32_t u32x2;

#define DEVI __device__ __forceinline__

constexpr int Bn = 2, Tn = 1024, Cn = 768, Hn = 12, HDn = 64;
constexpr int N3 = 3 * Cn;          // 2304
constexpr int Mrows = Bn * Tn;      // 2048
constexpr size_t SZy = (size_t)Mrows * Cn;  // elems per [B,T,C] slice

template <int V> struct IntC { static constexpr int value = V; };

DEVI short f2bf(float f) {
  union { float f; uint32_t u; } v; v.f = f;
  uint32_t u = v.u;
  return (short)((u + 0x7FFFu + ((u >> 16) & 1u)) >> 16);  // RNE
}
DEVI float bf2f(short b) {
  union { uint32_t u; float f; } v; v.u = ((uint32_t)(uint16_t)b) << 16;
  return v.f;
}
DEVI float fexp2(float x) { return __builtin_exp2f(x); }
// pack two f32 -> two bf16 in one u32 (RNE), single HW instr (T12)
DEVI uint32_t cvtpk(float lo, float hi) {
  uint32_t r;
  asm("v_cvt_pk_bf16_f32 %0, %1, %2" : "=v"(r) : "v"(lo), "v"(hi));
  return r;
}
// async global->LDS, 16B per lane. LDS dest = wave-uniform base + lane*16 (linear);
// global src is per-lane (pre-swizzle the source when a swizzled layout is wanted).
DEVI void cp16(void* lds, const void* g) {
  __builtin_amdgcn_global_load_lds(
      (const __attribute__((address_space(1))) uint32_t*)(uintptr_t)g,
      (__attribute__((address_space(3))) uint32_t*)(uint32_t)(uintptr_t)lds,
      16, 0, 0);
}
DEVI f32x4 fz() { f32x4 z; z[0] = 0.f; z[1] = 0.f; z[2] = 0.f; z[3] = 0.f; return z; }

// ---------------- merged prep kernel (fp32 -> bf16) ----------------
// blocks [0,1536):   x/xl/xu -> xb, mid, rad
// blocks [1536,3264): W_attn -> wb, |W| -> awb
// blocks [3264,3840): W_proj -> wpb
__global__ void prep_all(const float* __restrict__ x, const float* __restrict__ xl,
                         const float* __restrict__ xu, const float* __restrict__ Wa,
                         const float* __restrict__ Wp, short* __restrict__ xb,
                         short* __restrict__ mb, short* __restrict__ rb,
                         short* __restrict__ wb, short* __restrict__ awb,
                         short* __restrict__ wpb) {
  const int bid = blockIdx.x;
  if (bid < 1536) {
    int i = bid * 256 + threadIdx.x;
    float4 vx = ((const float4*)x)[i];
    float4 vl = ((const float4*)xl)[i];
    float4 vu = ((const float4*)xu)[i];
    s16x4 a, m_, g;
    a[0] = f2bf(vx.x); a[1] = f2bf(vx.y); a[2] = f2bf(vx.z); a[3] = f2bf(vx.w);
    m_[0] = f2bf(0.5f * (vl.x + vu.x)); m_[1] = f2bf(0.5f * (vl.y + vu.y));
    m_[2] = f2bf(0.5f * (vl.z + vu.z)); m_[3] = f2bf(0.5f * (vl.w + vu.w));
    g[0] = f2bf(0.5f * (vu.x - vl.x)); g[1] = f2bf(0.5f * (vu.y - vl.y));
    g[2] = f2bf(0.5f * (vu.z - vl.z)); g[3] = f2bf(0.5f * (vu.w - vl.w));
    ((s16x4*)xb)[i] = a; ((s16x4*)mb)[i] = m_; ((s16x4*)rb)[i] = g;
  } else if (bid < 3264) {
    int i = (bid - 1536) * 256 + threadIdx.x;
    float4 v = ((const float4*)Wa)[i];
    s16x4 a, b2;
    a[0] = f2bf(v.x); a[1] = f2bf(v.y); a[2] = f2bf(v.z); a[3] = f2bf(v.w);
    b2[0] = f2bf(fabsf(v.x)); b2[1] = f2bf(fabsf(v.y));
    b2[2] = f2bf(fabsf(v.z)); b2[3] = f2bf(fabsf(v.w));
    ((s16x4*)wb)[i] = a; ((s16x4*)awb)[i] = b2;
  } else {
    int i = (bid - 3264) * 256 + threadIdx.x;
    float4 v = ((const float4*)Wp)[i];
    s16x4 a;
    a[0] = f2bf(v.x); a[1] = f2bf(v.y); a[2] = f2bf(v.z); a[3] = f2bf(v.w);
    ((s16x4*)wpb)[i] = a;
  }
}

// ---------------- fused input GEMM: qkv / lower / upper in one launch ----------------
// acc0 = x @ W^T ; acc1 = mid @ W^T ; acc2 = rad @ |W|^T
// qkv = acc0 ; low = acc1 - acc2 ; up = acc1 + acc2
// BM=64, BN=128, wave-tile 32x64, grid(32, 18).  (R11-verified structure)
// (256,3): 170-VGPR budget. (256,4) caps at 128 and SPILLS (R9). grid.z split
// REGRESSED (R13). NEW R15: chunk-XOR LDS swizzle (c ^= row&3, both staging source
// and frag read — rule #21) spreads the 8-way bank conflict of 64B-stride frag
// reads to 4-way.
__launch_bounds__(256, 3)
__global__ void gemm_qkv3(const short* __restrict__ A0, const short* __restrict__ A1,
                          const short* __restrict__ A2, const short* __restrict__ B0,
                          const short* __restrict__ B1, short* __restrict__ qkv,
                          short* __restrict__ low, short* __restrict__ up) {
  constexpr int BM = 64, BN = 128;
  __shared__ short At[3 * BM * 32];   // 12 KB
  __shared__ short Bt[2 * BN * 32];   // 16 KB
  const int tid = threadIdx.x, wave = tid >> 6, lane = tid & 63;
  const int g = lane >> 4, q = lane & 15;
  const int wm = wave >> 1, wn = wave & 1;
  const int brow = blockIdx.x * BM, bcol = blockIdx.y * BN;
  const short* As[3] = {A0, A1, A2};
  const short* Bs[2] = {B0, B1};

  f32x4 acc[3][2][4];
#pragma unroll
  for (int a = 0; a < 3; a++)
#pragma unroll
    for (int m = 0; m < 2; m++)
#pragma unroll
      for (int n = 0; n < 4; n++) acc[a][m][n] = fz();

  const int arow = tid >> 2, ac = tid & 3;           // A: 1 chunk/thread per tile
  const int acs = ac ^ (arow & 3);                   // source chunk (pre-swizzle)
  for (int kt = 0; kt < Cn / 32; ++kt) {
#pragma unroll
    for (int a = 0; a < 3; a++)
      cp16((char*)At + a * 4096 + tid * 16,
           As[a] + (size_t)(brow + arow) * Cn + (kt * 32 + acs * 8));
#pragma unroll
    for (int b2 = 0; b2 < 2; b2++)
#pragma unroll
      for (int ii = 0; ii < 2; ++ii) {               // B: 128x32 tile, 2/thread
        int i = wave * 2 + ii;
        int ch = i * 64 + lane, row = ch >> 2, c = ch & 3;
        int cs = c ^ (row & 3);
        cp16((char*)Bt + b2 * 8192 + i * 1024,
             Bs[b2] + (size_t)(bcol + row) * Cn + (kt * 32 + cs * 8));
      }
    __syncthreads();
    bf16x8 bfr[2][4];
#pragma unroll
    for (int b2 = 0; b2 < 2; b2++)
#pragma unroll
      for (int n = 0; n < 4; n++) {
        int r = wn * 64 + n * 16 + q;
        bfr[b2][n] = *(const bf16x8*)&Bt[b2 * (BN * 32) + r * 32 + ((g ^ (r & 3)) * 8)];
      }
#pragma unroll
    for (int a = 0; a < 3; a++) {
      bf16x8 af[2];
#pragma unroll
      for (int m = 0; m < 2; m++) {
        int r = wm * 32 + m * 16 + q;
        af[m] = *(const bf16x8*)&At[a * (BM * 32) + r * 32 + ((g ^ (r & 3)) * 8)];
      }
      const int bs = (a == 2) ? 1 : 0;
#pragma unroll
      for (int m = 0; m < 2; m++)
#pragma unroll
        for (int n = 0; n < 4; n++)
          acc[a][m][n] = __builtin_amdgcn_mfma_f32_16x16x32_bf16(
              af[m], bfr[bs][n], acc[a][m][n], 0, 0, 0);
    }
    __syncthreads();
  }
#pragma unroll
  for (int m = 0; m < 2; m++)
#pragma unroll
    for (int n = 0; n < 4; n++)
#pragma unroll
      for (int r = 0; r < 4; r++) {
        int row = brow + wm * 32 + m * 16 + g * 4 + r;
        int col = bcol + wn * 64 + n * 16 + q;
        size_t idx = (size_t)row * N3 + col;
        float v0 = acc[0][m][n][r], v1 = acc[1][m][n][r], v2 = acc[2][m][n][r];
        qkv[idx] = f2bf(v0);
        low[idx] = f2bf(v1 - v2);
        up[idx]  = f2bf(v1 + v2);
      }
}

// ---------------- projection GEMM: 3 outputs in one launch (grid.z selects A) -------
// BM=64, BN=128, grid(32, 6, 3). (256,4) known-good. R15: same chunk-XOR swizzle.
__launch_bounds__(256, 4)
__global__ void gemm_proj(const short* __restrict__ A0, const short* __restrict__ A1,
                          const short* __restrict__ A2, const short* __restrict__ Bw,
                          float* __restrict__ out) {
  constexpr int BM = 64, BN = 128;
  __shared__ short At[BM * 32];
  __shared__ short Bt[BN * 32];
  const short* Ap = blockIdx.z == 0 ? A0 : (blockIdx.z == 1 ? A1 : A2);
  float* op = out + (size_t)blockIdx.z * SZy;
  const int tid = threadIdx.x, wave = tid >> 6, lane = tid & 63;
  const int g = lane >> 4, q = lane & 15;
  const int wm = wave >> 1, wn = wave & 1;
  const int brow = blockIdx.x * BM, bcol = blockIdx.y * BN;

  f32x4 acc[2][4];
#pragma unroll
  for (int m = 0; m < 2; m++)
#pragma unroll
    for (int n = 0; n < 4; n++) acc[m][n] = fz();

  const int chunk = wave * 64 + lane, srow = chunk >> 2, sc = chunk & 3;
  const int scs = sc ^ (srow & 3);                   // source chunk (pre-swizzle)
  for (int kt = 0; kt < Cn / 32; ++kt) {
    cp16((char*)At + wave * 1024, Ap + (size_t)(brow + srow) * Cn + (kt * 32 + scs * 8));
#pragma unroll
    for (int ii = 0; ii < 2; ++ii) {
      int i = wave * 2 + ii;
      int ch = i * 64 + lane, row = ch >> 2, c = ch & 3;
      int cs = c ^ (row & 3);
      cp16((char*)Bt + i * 1024, Bw + (size_t)(bcol + row) * Cn + (kt * 32 + cs * 8));
    }
    __syncthreads();
    bf16x8 af[2], bfr[4];
#pragma unroll
    for (int m = 0; m < 2; m++) {
      int r = wm * 32 + m * 16 + q;
      af[m] = *(const bf16x8*)&At[r * 32 + ((g ^ (r & 3)) * 8)];
    }
#pragma unroll
    for (int n = 0; n < 4; n++) {
      int r = wn * 64 + n * 16 + q;
      bfr[n] = *(const bf16x8*)&Bt[r * 32 + ((g ^ (r & 3)) * 8)];
    }
#pragma unroll
    for (int m = 0; m < 2; m++)
#pragma unroll
      for (int n = 0; n < 4; n++)
        acc[m][n] = __builtin_amdgcn_mfma_f32_16x16x32_bf16(af[m], bfr[n], acc[m][n], 0, 0, 0);
    __syncthreads();
  }
#pragma unroll
  for (int m = 0; m < 2; m++)
#pragma unroll
    for (int n = 0; n < 4; n++)
#pragma unroll
      for (int r = 0; r < 4; r++) {
        int row = brow + wm * 32 + m * 16 + g * 4 + r;
        int col = bcol + wn * 64 + n * 16 + q;
        op[(size_t)row * Cn + col] = acc[m][n][r];
      }
}

// ---------------- per-head V transpose (3 sources via grid.z) ----------------
__global__ void vtrans(const short* __restrict__ s0, const short* __restrict__ s1,
                       const short* __restrict__ s2, short* __restrict__ d0,
                       short* __restrict__ d1, short* __restrict__ d2) {
  __shared__ short tile[64][72];   // pad 8: rows stay 16B-aligned (144B)
  const short* src = blockIdx.z == 0 ? s0 : (blockIdx.z == 1 ? s1 : s2);
  short* dst = blockIdx.z == 0 ? d0 : (blockIdx.z == 1 ? d1 : d2);
  const int tt = blockIdx.x, bh = blockIdx.y;
  const int b = bh / Hn, h = bh % Hn;
  const int tid = threadIdx.x;
#pragma unroll
  for (int i = 0; i < 2; i++) {
    int chunk = i * 256 + tid;            // 512 chunks of 8 elems
    int t = chunk >> 3, c = chunk & 7;
    s16x8 v = *(const s16x8*)(src + (size_t)(b * Tn + tt * 64 + t) * N3 +
                              2 * Cn + h * HDn + c * 8);
    *(s16x8*)&tile[t][c * 8] = v;
  }
  __syncthreads();
#pragma unroll
  for (int i = 0; i < 2; i++) {
    int chunk = i * 256 + tid;
    int d = chunk >> 3, tc = chunk & 7;
    s16x8 v;
#pragma unroll
    for (int j = 0; j < 8; j++) v[j] = tile[tc * 8 + j][d];
    *(s16x8*)(dst + (size_t)bh * (64 * 1024) + (size_t)d * 1024 + tt * 64 + tc * 8) = v;
  }
}

// ---------------- unified flash attention (causal, swapped-QK^T, QBLK=128) --------
// grid (24 bh, 5 combo, 8 j-reversed). Each wave owns TWO 16-row q-groups (u=0,1)
// 64 rows apart: every K/V LDS A-frag read feeds 2 MFMAs. combo 0..3 = (q,k) bound
// pairs (min = P vL, max = P vU since P >= 0); combo 4 = main.
// (256,3): 84 VGPR, no spill (R11/R14: 51.4 us). (256,4) SPILLS (R10). V-in-reg
// uncoalesced+spill (R12). Dbuf/counted-vmcnt neutral (R7). R14-EXACT.
__launch_bounds__(256, 3)
__global__ void flash_all(const short* __restrict__ qkv, const short* __restrict__ lowb,
                          const short* __restrict__ upb, const short* __restrict__ vtq,
                          const short* __restrict__ vtl, const short* __restrict__ vtu,
                          short* __restrict__ yab, short* __restrict__ comb) {
  constexpr float SCL = 0.18033688f;       // (1/sqrt(64)) * log2(e)
  constexpr float THR = 8.0f / SCL;        // defer-max threshold, raw-score domain
  __shared__ short Kt[64 * 64];            // 8 KB (source pre-XOR-swizzled)
  __shared__ short Vt0[64 * 64];           // 8 KB
  __shared__ short Vt1[64 * 64];           // 8 KB
  __shared__ short Pt[8 * 16 * 64];        // 16 KB: per (wave,u) 16q x 64k P^T
  const int tid = threadIdx.x, wave = tid >> 6, lane = tid & 63;
  const int g = lane >> 4, q = lane & 15;
  const int bh = blockIdx.x, combo = blockIdx.y;
  const int j = 7 - blockIdx.z;            // long blocks dispatch first
  const int qt0 = j * 128;
  const int b = bh / Hn, h = bh % Hn;
  const bool isMain = (combo == 4);
  const short* Qsrc = isMain ? qkv : ((combo & 2) ? upb : lowb);
  const short* Ksrc = isMain ? qkv : ((combo & 1) ? upb : lowb);
  const short* V0t = isMain ? vtq : vtl;
  const short* V1t = vtu;
  const int qswz = (q & 7) << 4;

  // staging source offsets (lane-dependent, kv-invariant)
  int koff[2], voff[2];
#pragma unroll
  for (int ii = 0; ii < 2; ++ii) {
    int chunk = (wave * 2 + ii) * 64 + lane, row = chunk >> 3, c = chunk & 7;
    int cg = c ^ (row & 7);
    koff[ii] = row * N3 + cg * 8;
    voff[ii] = row * 1024 + cg * 8;
  }
  const short* Kbase = Ksrc + (size_t)(b * Tn) * N3 + Cn + h * HDn;
  const short* V0base = V0t + (size_t)bh * (64 * 1024);
  const short* V1base = V1t + (size_t)bh * (64 * 1024);

  // Q frags (PV-style B-frag): lane holds Q[q][8 contiguous d]
  bf16x8 aq[2][2];
#pragma unroll
  for (int u = 0; u < 2; u++) {
    int trow = qt0 + u * 64 + wave * 16 + q;
    const short* qp = Qsrc + (size_t)(b * Tn + trow) * N3 + h * HDn;
#pragma unroll
    for (int s = 0; s < 2; s++) aq[u][s] = *(const bf16x8*)(qp + s * 32 + g * 8);
  }

  f32x4 o0[2][4], o1[2][4];     // o[u][mf][r]: d = mf*16 + g*4 + r, col q
  float mrow[2], lrow[2];
#pragma unroll
  for (int u = 0; u < 2; u++) {
    mrow[u] = -INFINITY; lrow[u] = 0.f;
#pragma unroll
    for (int n = 0; n < 4; n++) { o0[u][n] = fz(); o1[u][n] = fz(); }
  }

  // softmax for one q-group; sv = S^T fragment (k = m*16+g*4+r, col q)
  auto softmax_u = [&](f32x4 (&sv)[4], int u, auto diagc) {
    constexpr bool DIAG = decltype(diagc)::value;
    if constexpr (DIAG) {
      const int rhs = wave * 16 + q, kb = g * 4;
#pragma unroll
      for (int m = 0; m < 4; m++)
#pragma unroll
        for (int r = 0; r < 4; r++)
          sv[m][r] = (m * 16 + kb + r <= rhs) ? sv[m][r] : -INFINITY;
    }
    float mx = -INFINITY;
#pragma unroll
    for (int m = 0; m < 4; m++)
#pragma unroll
      for (int r = 0; r < 4; r++) mx = fmaxf(mx, sv[m][r]);
    mx = fmaxf(mx, __shfl_xor(mx, 16));
    mx = fmaxf(mx, __shfl_xor(mx, 32));
    if (!__all(mx <= mrow[u] + THR)) {     // defer-max (T13)
      float mnew = fmaxf(mrow[u], mx);
      float corr = fexp2((mrow[u] - mnew) * SCL);
      mrow[u] = mnew; lrow[u] *= corr;
#pragma unroll
      for (int n = 0; n < 4; n++) {
        o0[u][n][0] *= corr; o0[u][n][1] *= corr;
        o0[u][n][2] *= corr; o0[u][n][3] *= corr;
      }
      if (!isMain) {
#pragma unroll
        for (int n = 0; n < 4; n++) {
          o1[u][n][0] *= corr; o1[u][n][1] *= corr;
          o1[u][n][2] *= corr; o1[u][n][3] *= corr;
        }
      }
    }
    const float nms = -mrow[u] * SCL;
    float ps = 0.f;
#pragma unroll
    for (int m = 0; m < 4; m++)
#pragma unroll
      for (int r = 0; r < 4; r++) {
        float p = fexp2(fmaf(sv[m][r], SCL, nms));
        sv[m][r] = p;
        ps += p;
      }
    ps += __shfl_xor(ps, 16);
    ps += __shfl_xor(ps, 32);
    lrow[u] += ps;
    // P^T -> Pt (b64 stores; wave-private, same-wave in-order write->read)
    char* PtW = (char*)Pt + (wave * 2 + u) * 2048;
#pragma unroll
    for (int m = 0; m < 4; m++) {
      u32x2 w;
      w[0] = cvtpk(sv[m][0], sv[m][1]);
      w[1] = cvtpk(sv[m][2], sv[m][3]);
      *(u32x2*)(PtW + ((q * 128 + m * 32 + g * 8) ^ qswz)) = w;
    }
  };

  // one kv tile; M0/M1 per-group mode: 2=full, 1=diag, 0=skip
  auto kv_iter = [&](int kv, auto m0c, auto m1c) {
    constexpr int M0 = decltype(m0c)::value;
    constexpr int M1 = decltype(m1c)::value;
    // stage K/V tiles (pre-swizzled source -> linear LDS; reads XOR back)
#pragma unroll
    for (int ii = 0; ii < 2; ++ii)
      cp16((char*)Kt + (wave * 2 + ii) * 1024, Kbase + (size_t)kv * (64 * N3) + koff[ii]);
#pragma unroll
    for (int ii = 0; ii < 2; ++ii)
      cp16((char*)Vt0 + (wave * 2 + ii) * 1024, V0base + kv * 64 + voff[ii]);
    if (!isMain) {
#pragma unroll
      for (int ii = 0; ii < 2; ++ii)
        cp16((char*)Vt1 + (wave * 2 + ii) * 1024, V1base + kv * 64 + voff[ii]);
    }
    __syncthreads();

    // S^T = K Q^T for both q-groups: one bk read feeds 2 MFMAs
    f32x4 sa0[4], sa1[4];
#pragma unroll
    for (int m = 0; m < 4; m++) { sa0[m] = fz(); sa1[m] = fz(); }
    __builtin_amdgcn_s_setprio(1);
#pragma unroll
    for (int m = 0; m < 4; m++) {
#pragma unroll
      for (int s = 0; s < 2; s++) {
        int krow = m * 16 + q;
        bf16x8 bk = *(const bf16x8*)((char*)Kt +
            krow * 128 + ((g * 16 + s * 64) ^ ((krow & 7) << 4)));
        if constexpr (M0 > 0)
          sa0[m] = __builtin_amdgcn_mfma_f32_16x16x32_bf16(bk, aq[0][s], sa0[m], 0, 0, 0);
        if constexpr (M1 > 0)
          sa1[m] = __builtin_amdgcn_mfma_f32_16x16x32_bf16(bk, aq[1][s], sa1[m], 0, 0, 0);
      }
    }
    __builtin_amdgcn_s_setprio(0);

    if constexpr (M0 > 0) softmax_u(sa0, 0, IntC<(M0 == 1)>{});
    if constexpr (M1 > 0) softmax_u(sa1, 1, IntC<(M1 == 1)>{});

    // O^T += V^T P^T: one V read feeds 2 MFMAs (u=0,1)
    __builtin_amdgcn_s_setprio(1);
#pragma unroll
    for (int kk = 0; kk < 2; kk++) {
      bf16x8 pb0, pb1;
      if constexpr (M0 > 0)
        pb0 = *(const bf16x8*)((char*)Pt + (wave * 2 + 0) * 2048 +
                               ((q * 128 + kk * 64 + g * 16) ^ qswz));
      if constexpr (M1 > 0)
        pb1 = *(const bf16x8*)((char*)Pt + (wave * 2 + 1) * 2048 +
                               ((q * 128 + kk * 64 + g * 16) ^ qswz));
#pragma unroll
      for (int mf = 0; mf < 4; mf++) {
        int drow = mf * 16 + q;
        int boff = drow * 128 + ((g * 16 + kk * 64) ^ ((drow & 7) << 4));
        bf16x8 av0 = *(const bf16x8*)((char*)Vt0 + boff);
        if constexpr (M0 > 0)
          o0[0][mf] = __builtin_amdgcn_mfma_f32_16x16x32_bf16(av0, pb0, o0[0][mf], 0, 0, 0);
        if constexpr (M1 > 0)
          o0[1][mf] = __builtin_amdgcn_mfma_f32_16x16x32_bf16(av0, pb1, o0[1][mf], 0, 0, 0);
        if (!isMain) {
          bf16x8 av1 = *(const bf16x8*)((char*)Vt1 + boff);
          if constexpr (M0 > 0)
            o1[0][mf] = __builtin_amdgcn_mfma_f32_16x16x32_bf16(av1, pb0, o1[0][mf], 0, 0, 0);
          if constexpr (M1 > 0)
            o1[1][mf] = __builtin_amdgcn_mfma_f32_16x16x32_bf16(av1, pb1, o1[1][mf], 0, 0, 0);
        }
      }
    }
    __builtin_amdgcn_s_setprio(0);
    __syncthreads();
  };

  const int jj = 2 * j;                    // diag tile of group 0
  for (int kv = 0; kv < jj; ++kv) kv_iter(kv, IntC<2>{}, IntC<2>{});
  kv_iter(jj, IntC<1>{}, IntC<2>{});
  kv_iter(jj + 1, IntC<0>{}, IntC<1>{});

  // epilogue: lane owns row q of group u; packed 8B stores
#pragma unroll
  for (int u = 0; u < 2; u++) {
    const float inv = 1.0f / lrow[u];
    const int trow = qt0 + u * 64 + wave * 16 + q;
    const size_t rowbase = (size_t)(b * Tn + trow) * Cn + h * HDn + g * 4;
#pragma unroll
    for (int mf = 0; mf < 4; mf++) {
      size_t idx = rowbase + mf * 16;
      u32x2 v0;
      v0[0] = cvtpk(o0[u][mf][0] * inv, o0[u][mf][1] * inv);
      v0[1] = cvtpk(o0[u][mf][2] * inv, o0[u][mf][3] * inv);
      if (isMain) {
        *(u32x2*)(yab + idx) = v0;
      } else {
        u32x2 v1;
        v1[0] = cvtpk(o1[u][mf][0] * inv, o1[u][mf][1] * inv);
        v1[1] = cvtpk(o1[u][mf][2] * inv, o1[u][mf][3] * inv);
        // P >= 0 and vL <= vU  =>  P vL <= P vU elementwise
        *(u32x2*)(comb + (size_t)(2 * combo) * SZy + idx) = v0;
        *(u32x2*)(comb + (size_t)(2 * combo + 1) * SZy + idx) = v1;
      }
    }
  }
}

// ---------------- min/max reduce over the 4 bound combos ----------------
__global__ void reduce_minmax(const short* __restrict__ comb, short* __restrict__ ymn,
                              short* __restrict__ ymx) {
  int i = blockIdx.x * 256 + threadIdx.x;   // 8 elems/thread; grid = SZy/8/256 = 768
  s16x8 mn8 = ((const s16x8*)(comb + 0 * SZy))[i];
  s16x8 mx8 = ((const s16x8*)(comb + 1 * SZy))[i];
#pragma unroll
  for (int c = 1; c < 4; c++) {
    s16x8 a = ((const s16x8*)(comb + (size_t)(2 * c) * SZy))[i];
    s16x8 b2 = ((const s16x8*)(comb + (size_t)(2 * c + 1) * SZy))[i];
#pragma unroll
    for (int j = 0; j < 8; j++) {
      mn8[j] = f2bf(fminf(bf2f(mn8[j]), bf2f(a[j])));
      mx8[j] = f2bf(fmaxf(bf2f(mx8[j]), bf2f(b2[j])));
    }
  }
  ((s16x8*)ymn)[i] = mn8;
  ((s16x8*)ymx)[i] = mx8;
}

// ---------------- launch ----------------
extern "C" void kernel_launch(void* const* d_in, const int* in_sizes, int n_in,
                              void* d_out, int out_size, void* d_ws, size_t ws_size,
                              hipStream_t stream) {
  const float* x  = (const float*)d_in[0];
  const float* xl = (const float*)d_in[1];
  const float* xu = (const float*)d_in[2];
  const float* Wa = (const float*)d_in[3];
  const float* Wp = (const float*)d_in[4];
  float* out = (float*)d_out;

  char* p = (char*)d_ws;
  auto carve = [&](size_t bytes) -> char* {
    char* r = p; p += (bytes + 255) & ~(size_t)255; return r;
  };
  short* xb   = (short*)carve((size_t)Mrows * Cn * 2);
  short* midb = (short*)carve((size_t)Mrows * Cn * 2);
  short* radb = (short*)carve((size_t)Mrows * Cn * 2);
  short* wb   = (short*)carve((size_t)N3 * Cn * 2);
  short* awb  = (short*)carve((size_t)N3 * Cn * 2);
  short* wpb  = (short*)carve((size_t)Cn * Cn * 2);
  short* qkvb = (short*)carve((size_t)Mrows * N3 * 2);
  short* lowb = (short*)carve((size_t)Mrows * N3 * 2);
  short* upb  = (short*)carve((size_t)Mrows * N3 * 2);
  short* vtq  = (short*)carve((size_t)24 * 64 * 1024 * 2);
  short* vtl  = (short*)carve((size_t)24 * 64 * 1024 * 2);
  short* vtu  = (short*)carve((size_t)24 * 64 * 1024 * 2);
  short* yab  = (short*)carve(SZy * 2);
  short* ymnb = (short*)carve(SZy * 2);
  short* ymxb = (short*)carve(SZy * 2);
  short* comb = (short*)carve(8 * SZy * 2);

  // all bf16 conversions (+ mid/rad, |W|) in ONE launch
  prep_all<<<3840, 256, 0, stream>>>(x, xl, xu, Wa, Wp, xb, midb, radb,
                                     wb, awb, wpb);

  // qkv / lower / upper in one fused launch (R11 structure + LDS swizzle)
  gemm_qkv3<<<dim3(32, 18), 256, 0, stream>>>(xb, midb, radb, wb, awb,
                                              qkvb, lowb, upb);

  // per-head V transposes (3 sources, one launch)
  vtrans<<<dim3(16, 24, 3), 256, 0, stream>>>(qkvb, lowb, upb, vtq, vtl, vtu);

  // all 5 attention passes in one launch (QBLK=128) — R14-exact
  flash_all<<<dim3(24, 5, 8), 256, 0, stream>>>(qkvb, lowb, upb, vtq, vtl, vtu,
                                                yab, comb);

  // fold the 4 bound combos into ymin/ymax
  reduce_minmax<<<768, 256, 0, stream>>>(comb, ymnb, ymxb);

  // output projections -> d_out (y, y_lower, y_upper) in one launch
  gemm_proj<<<dim3(32, 6, 3), 256, 0, stream>>>(yab, ymnb, ymxb, wpb, out);
}